// Round 1
// baseline (6363.720 us; speedup 1.0000x reference)
//
#include <hip/hip_runtime.h>
#include <hip/hip_bf16.h>

#define N_EDGES 800000
#define N_NODES 50000
#define MUL 32

#define S2   0.7071067811865475f
#define S2_3 0.4082482904638631f
#define INV_SQRT_MUL 0.17677669529663687f

__device__ __forceinline__ float silu_f(float x) {
    return x / (1.0f + __expf(-x));
}

// ---------------- self-connection kernel: writes (initializes) d_out ----------------
__global__ __launch_bounds__(256)
void sc_kernel(const float* __restrict__ node_feat,
               const float* __restrict__ sc_w0,
               const float* __restrict__ sc_w1,
               float* __restrict__ out)
{
    __shared__ float sw0[1024];
    __shared__ float sw1[1024];
    __shared__ float xrow[256];

    const int t = threadIdx.x;
    // stage 32x32 weights (1024 floats = 256 float4 each)
    ((float4*)sw0)[t] = ((const float4*)sc_w0)[t];
    ((float4*)sw1)[t] = ((const float4*)sc_w1)[t];
    __syncthreads();

    const int half = t >> 7;   // which of 2 nodes this iteration
    const int c    = t & 127;  // output column

    for (int it = 0; it < 4; ++it) {
        const int n = blockIdx.x * 8 + it * 2 + half;
        if (it) __syncthreads();           // protect xrow reuse
        xrow[t] = node_feat[(size_t)n * 128 + c];
        __syncthreads();
        const float* xr = xrow + half * 128;

        float acc = 0.0f;
        if (c < 32) {
            const int v = c;
            #pragma unroll
            for (int u = 0; u < 32; ++u) acc += xr[u] * sw0[u * 32 + v];
        } else {
            const int i = c - 32;
            const int v = i / 3;
            const int j = i - 3 * v;
            #pragma unroll
            for (int u = 0; u < 32; ++u) acc += xr[32 + u * 3 + j] * sw1[u * 32 + v];
        }
        out[(size_t)n * 128 + c] = acc * INV_SQRT_MUL;
    }
}

// ---------------- edge kernel: MLP + tensor-product message + atomic scatter ----------------
__global__ __launch_bounds__(256, 2)
void edge_kernel(const int* __restrict__ ei,
                 const float* __restrict__ node_feat,
                 const float* __restrict__ edge_feat,
                 const float* __restrict__ edge_embed,
                 const float* __restrict__ W1, const float* __restrict__ B1,
                 const float* __restrict__ W2, const float* __restrict__ B2,
                 const float* __restrict__ W3, const float* __restrict__ B3,
                 float* __restrict__ out)
{
    __shared__ float sW1[2048];
    __shared__ float sB1[64];
    __shared__ float sW2[2048];
    __shared__ float sB2[32];
    __shared__ float sW3[4096];
    __shared__ float sB3[128];

    const int t = threadIdx.x;
    // stage weights (vectorized)
    {
        const float4* w1v = (const float4*)W1;
        const float4* w2v = (const float4*)W2;
        const float4* w3v = (const float4*)W3;
        ((float4*)sW1)[t]       = w1v[t];
        ((float4*)sW1)[t + 256] = w1v[t + 256];
        ((float4*)sW2)[t]       = w2v[t];
        ((float4*)sW2)[t + 256] = w2v[t + 256];
        #pragma unroll
        for (int i = 0; i < 4; ++i) ((float4*)sW3)[t + 256 * i] = w3v[t + 256 * i];
        if (t < 64)  sB1[t] = B1[t];
        if (t < 32)  sB2[t] = B2[t];
        if (t < 128) sB3[t] = B3[t];
    }
    __syncthreads();

    const int e   = blockIdx.x * 256 + t;     // grid covers exactly 800000
    const int src = ei[e];
    const int dst = ei[N_EDGES + e];

    // ---- load edge embedding (32 floats) ----
    float emb[32];
    {
        const float4* ev = (const float4*)(edge_embed + (size_t)e * 32);
        #pragma unroll
        for (int i = 0; i < 8; ++i) {
            float4 v = ev[i];
            emb[4 * i]     = v.x;
            emb[4 * i + 1] = v.y;
            emb[4 * i + 2] = v.z;
            emb[4 * i + 3] = v.w;
        }
    }

    // ---- h1 = silu(emb @ W1 + b1)  (64) ----
    float h1[64];
    #pragma unroll
    for (int o = 0; o < 64; ++o) h1[o] = sB1[o];
    #pragma unroll
    for (int u = 0; u < 32; ++u) {
        const float x = emb[u];
        const float4* wr = (const float4*)(sW1 + u * 64);
        #pragma unroll
        for (int o4 = 0; o4 < 16; ++o4) {
            float4 w = wr[o4];
            h1[4 * o4]     += x * w.x;
            h1[4 * o4 + 1] += x * w.y;
            h1[4 * o4 + 2] += x * w.z;
            h1[4 * o4 + 3] += x * w.w;
        }
    }
    #pragma unroll
    for (int o = 0; o < 64; ++o) h1[o] = silu_f(h1[o]);

    // ---- h2 = silu(h1 @ W2 + b2)  (32) ----
    float h2[32];
    #pragma unroll
    for (int v = 0; v < 32; ++v) h2[v] = sB2[v];
    #pragma unroll
    for (int k = 0; k < 64; ++k) {
        const float x = h1[k];
        const float4* wr = (const float4*)(sW2 + k * 32);
        #pragma unroll
        for (int v4 = 0; v4 < 8; ++v4) {
            float4 w = wr[v4];
            h2[4 * v4]     += x * w.x;
            h2[4 * v4 + 1] += x * w.y;
            h2[4 * v4 + 2] += x * w.z;
            h2[4 * v4 + 3] += x * w.w;
        }
    }
    #pragma unroll
    for (int v = 0; v < 32; ++v) h2[v] = silu_f(h2[v]);

    // ---- w = h2 @ W3 + b3  (128) split into 4 chunks of 32 ----
    float wv[4][32];
    #pragma unroll
    for (int c = 0; c < 4; ++c)
        #pragma unroll
        for (int u = 0; u < 32; ++u) wv[c][u] = sB3[c * 32 + u];
    #pragma unroll
    for (int k = 0; k < 32; ++k) {
        const float x = h2[k];
        const float4* wr = (const float4*)(sW3 + k * 128);
        #pragma unroll
        for (int q = 0; q < 32; ++q) {
            float4 w = wr[q];
            const int c  = q >> 3;
            const int u0 = (q & 7) * 4;
            wv[c][u0]     += x * w.x;
            wv[c][u0 + 1] += x * w.y;
            wv[c][u0 + 2] += x * w.z;
            wv[c][u0 + 3] += x * w.w;
        }
    }

    // ---- message + atomic scatter ----
    const float4 ef = *(const float4*)(edge_feat + (size_t)e * 4);
    const float e0  = ef.x;
    const float e1x = ef.y, e1y = ef.z, e1z = ef.w;

    const float4* xrow4 = (const float4*)(node_feat + (size_t)src * 128);
    float* orow = out + (size_t)dst * 128;

    #pragma unroll
    for (int ug = 0; ug < 8; ++ug) {
        const float4 x0v = xrow4[ug];
        const float4 xa  = xrow4[8 + 3 * ug];
        const float4 xb  = xrow4[9 + 3 * ug];
        const float4 xc  = xrow4[10 + 3 * ug];
        const float x0[4]    = {x0v.x, x0v.y, x0v.z, x0v.w};
        const float x1[4][3] = {{xa.x, xa.y, xa.z},
                                {xa.w, xb.x, xb.y},
                                {xb.z, xb.w, xc.x},
                                {xc.y, xc.z, xc.w}};
        #pragma unroll
        for (int q = 0; q < 4; ++q) {
            const int u = ug * 4 + q;
            const float w000 = wv[0][u];
            const float w011 = wv[1][u];
            const float w101 = wv[2][u];
            const float w110 = wv[3][u];
            const float dot = x1[q][0] * e1x + x1[q][1] * e1y + x1[q][2] * e1z;
            const float o0  = S2 * w000 * x0[q] * e0 + S2_3 * w110 * dot;
            unsafeAtomicAdd(orow + u, o0);
            const float a = S2 * w011 * x0[q];
            const float b = S2 * w101 * e0;
            unsafeAtomicAdd(orow + 32 + 3 * u + 0, a * e1x + b * x1[q][0]);
            unsafeAtomicAdd(orow + 32 + 3 * u + 1, a * e1y + b * x1[q][1]);
            unsafeAtomicAdd(orow + 32 + 3 * u + 2, a * e1z + b * x1[q][2]);
        }
    }
}

extern "C" void kernel_launch(void* const* d_in, const int* in_sizes, int n_in,
                              void* d_out, int out_size, void* d_ws, size_t ws_size,
                              hipStream_t stream)
{
    const int*   ei         = (const int*)  d_in[0];
    const float* node_feat  = (const float*)d_in[1];
    const float* edge_feat  = (const float*)d_in[2];
    const float* edge_embed = (const float*)d_in[3];
    const float* fc_w1      = (const float*)d_in[4];
    const float* fc_b1      = (const float*)d_in[5];
    const float* fc_w2      = (const float*)d_in[6];
    const float* fc_b2      = (const float*)d_in[7];
    const float* fc_w3      = (const float*)d_in[8];
    const float* fc_b3      = (const float*)d_in[9];
    const float* sc_w0      = (const float*)d_in[10];
    const float* sc_w1      = (const float*)d_in[11];
    float* out = (float*)d_out;

    // 1) self-connection: fully writes d_out (50000 nodes, 8 per block)
    sc_kernel<<<N_NODES / 8, 256, 0, stream>>>(node_feat, sc_w0, sc_w1, out);

    // 2) edges: MLP + message + atomic aggregation (800000 edges, 256 per block)
    edge_kernel<<<N_EDGES / 256, 256, 0, stream>>>(ei, node_feat, edge_feat, edge_embed,
                                                   fc_w1, fc_b1, fc_w2, fc_b2, fc_w3, fc_b3,
                                                   out);
}

// Round 2
// 3169.165 us; speedup vs baseline: 2.0080x; 2.0080x over previous
//
#include <hip/hip_runtime.h>
#include <hip/hip_bf16.h>

#define N_EDGES 800000
#define N_NODES 50000
#define NPB 32            // nodes per gather block (must be power of 2, <= 32 for packing)
#define ACC_STRIDE 129    // 128 + 1 pad -> bank = (local + f) % 32, ~2-way (free)

#define S2   0.7071067811865475f
#define S2_3 0.4082482904638631f
#define INV_SQRT_MUL 0.17677669529663687f

__device__ __forceinline__ float silu_f(float x) {
    return x / (1.0f + __expf(-x));
}

// ---------------- CSR build: histogram ----------------
__global__ __launch_bounds__(256)
void hist_kernel(const int* __restrict__ ei, int* __restrict__ counts)
{
    const int e = blockIdx.x * 256 + threadIdx.x;
    if (e < N_EDGES) atomicAdd(&counts[ei[N_EDGES + e]], 1);
}

// ---------------- CSR build: single-block scan (exclusive) ----------------
__global__ __launch_bounds__(1024)
void scan_kernel(const int* __restrict__ counts,
                 int* __restrict__ row_ptr,
                 int* __restrict__ cursor)
{
    __shared__ int buf[1024];
    __shared__ int s_carry;
    const int t = threadIdx.x;
    if (t == 0) s_carry = 0;
    __syncthreads();

    for (int base = 0; base < N_NODES; base += 4096) {
        const int idx0 = base + t * 4;
        int v[4];
        #pragma unroll
        for (int k = 0; k < 4; ++k) {
            const int i = idx0 + k;
            v[k] = (i < N_NODES) ? counts[i] : 0;
        }
        const int tsum = v[0] + v[1] + v[2] + v[3];
        buf[t] = tsum;
        __syncthreads();
        // Hillis-Steele inclusive scan over 1024 thread-sums
        for (int off = 1; off < 1024; off <<= 1) {
            const int x = (t >= off) ? buf[t - off] : 0;
            __syncthreads();
            buf[t] += x;
            __syncthreads();
        }
        const int carry = s_carry;
        int excl = carry + buf[t] - tsum;
        #pragma unroll
        for (int k = 0; k < 4; ++k) {
            const int i = idx0 + k;
            if (i < N_NODES) { row_ptr[i] = excl; cursor[i] = excl; }
            excl += v[k];
        }
        const int total = buf[1023];
        __syncthreads();
        if (t == 0) s_carry = carry + total;
        __syncthreads();
    }
    if (t == 0) row_ptr[N_NODES] = s_carry;   // == N_EDGES
}

// ---------------- CSR build: scatter edge ids (packed with local node idx) ----------------
__global__ __launch_bounds__(256)
void scatter_kernel(const int* __restrict__ ei,
                    int* __restrict__ cursor,
                    int* __restrict__ csr)
{
    const int e = blockIdx.x * 256 + threadIdx.x;
    if (e < N_EDGES) {
        const int dst = ei[N_EDGES + e];
        const int pos = atomicAdd(&cursor[dst], 1);
        // e < 2^20, local (dst % NPB) in bits 20..24
        csr[pos] = e | ((dst & (NPB - 1)) << 20);
    }
}

// ---------------- self-connection kernel: writes (initializes) d_out ----------------
__global__ __launch_bounds__(256)
void sc_kernel(const float* __restrict__ node_feat,
               const float* __restrict__ sc_w0,
               const float* __restrict__ sc_w1,
               float* __restrict__ out)
{
    __shared__ float sw0[1024];
    __shared__ float sw1[1024];
    __shared__ float xrow[256];

    const int t = threadIdx.x;
    ((float4*)sw0)[t] = ((const float4*)sc_w0)[t];
    ((float4*)sw1)[t] = ((const float4*)sc_w1)[t];
    __syncthreads();

    const int half = t >> 7;
    const int c    = t & 127;

    for (int it = 0; it < 4; ++it) {
        const int n = blockIdx.x * 8 + it * 2 + half;
        if (it) __syncthreads();
        xrow[t] = node_feat[(size_t)n * 128 + c];
        __syncthreads();
        const float* xr = xrow + half * 128;

        float acc = 0.0f;
        if (c < 32) {
            const int v = c;
            #pragma unroll
            for (int u = 0; u < 32; ++u) acc += xr[u] * sw0[u * 32 + v];
        } else {
            const int i = c - 32;
            const int v = i / 3;
            const int j = i - 3 * v;
            #pragma unroll
            for (int u = 0; u < 32; ++u) acc += xr[32 + u * 3 + j] * sw1[u * 32 + v];
        }
        out[(size_t)n * 128 + c] = acc * INV_SQRT_MUL;
    }
}

// ---------------- gather kernel: per-node-block edge MLP + LDS aggregation ----------------
__global__ __launch_bounds__(256, 2)
void gather_kernel(const int* __restrict__ ei,
                   const int* __restrict__ row_ptr,
                   const int* __restrict__ csr,
                   const float* __restrict__ node_feat,
                   const float* __restrict__ edge_feat,
                   const float* __restrict__ edge_embed,
                   const float* __restrict__ W1, const float* __restrict__ B1,
                   const float* __restrict__ W2, const float* __restrict__ B2,
                   const float* __restrict__ W3, const float* __restrict__ B3,
                   float* __restrict__ out)
{
    __shared__ float sW1[2048];
    __shared__ float sB1[64];
    __shared__ float sW2[2048];
    __shared__ float sB2[32];
    __shared__ float sW3[4096];
    __shared__ float sB3[128];
    __shared__ float accum[NPB * ACC_STRIDE];

    const int t = threadIdx.x;
    // stage weights (vectorized) + zero accumulator
    {
        const float4* w1v = (const float4*)W1;
        const float4* w2v = (const float4*)W2;
        const float4* w3v = (const float4*)W3;
        ((float4*)sW1)[t]       = w1v[t];
        ((float4*)sW1)[t + 256] = w1v[t + 256];
        ((float4*)sW2)[t]       = w2v[t];
        ((float4*)sW2)[t + 256] = w2v[t + 256];
        #pragma unroll
        for (int i = 0; i < 4; ++i) ((float4*)sW3)[t + 256 * i] = w3v[t + 256 * i];
        if (t < 64)  sB1[t] = B1[t];
        if (t < 32)  sB2[t] = B2[t];
        if (t < 128) sB3[t] = B3[t];
        for (int i = t; i < NPB * ACC_STRIDE; i += 256) accum[i] = 0.0f;
    }
    __syncthreads();

    const int node_base = blockIdx.x * NPB;
    const int nb_end    = (node_base + NPB < N_NODES) ? node_base + NPB : N_NODES;
    const int start     = row_ptr[node_base];
    const int end       = row_ptr[nb_end];

    for (int i = start + t; i < end; i += 256) {
        const int entry = csr[i];
        const int e     = entry & 0xFFFFF;
        const int local = entry >> 20;
        const int src   = ei[e];

        // ---- load edge embedding (32 floats) ----
        float emb[32];
        {
            const float4* ev = (const float4*)(edge_embed + (size_t)e * 32);
            #pragma unroll
            for (int k = 0; k < 8; ++k) {
                float4 v = ev[k];
                emb[4 * k]     = v.x;
                emb[4 * k + 1] = v.y;
                emb[4 * k + 2] = v.z;
                emb[4 * k + 3] = v.w;
            }
        }

        // ---- h1 = silu(emb @ W1 + b1) ----
        float h1[64];
        #pragma unroll
        for (int o = 0; o < 64; ++o) h1[o] = sB1[o];
        #pragma unroll
        for (int u = 0; u < 32; ++u) {
            const float x = emb[u];
            const float4* wr = (const float4*)(sW1 + u * 64);
            #pragma unroll
            for (int o4 = 0; o4 < 16; ++o4) {
                float4 w = wr[o4];
                h1[4 * o4]     += x * w.x;
                h1[4 * o4 + 1] += x * w.y;
                h1[4 * o4 + 2] += x * w.z;
                h1[4 * o4 + 3] += x * w.w;
            }
        }
        #pragma unroll
        for (int o = 0; o < 64; ++o) h1[o] = silu_f(h1[o]);

        // ---- h2 = silu(h1 @ W2 + b2) ----
        float h2[32];
        #pragma unroll
        for (int v = 0; v < 32; ++v) h2[v] = sB2[v];
        #pragma unroll
        for (int k = 0; k < 64; ++k) {
            const float x = h1[k];
            const float4* wr = (const float4*)(sW2 + k * 32);
            #pragma unroll
            for (int v4 = 0; v4 < 8; ++v4) {
                float4 w = wr[v4];
                h2[4 * v4]     += x * w.x;
                h2[4 * v4 + 1] += x * w.y;
                h2[4 * v4 + 2] += x * w.z;
                h2[4 * v4 + 3] += x * w.w;
            }
        }
        #pragma unroll
        for (int v = 0; v < 32; ++v) h2[v] = silu_f(h2[v]);

        // ---- w = h2 @ W3 + b3 (128) ----
        float wv[4][32];
        #pragma unroll
        for (int c = 0; c < 4; ++c)
            #pragma unroll
            for (int u = 0; u < 32; ++u) wv[c][u] = sB3[c * 32 + u];
        #pragma unroll
        for (int k = 0; k < 32; ++k) {
            const float x = h2[k];
            const float4* wr = (const float4*)(sW3 + k * 128);
            #pragma unroll
            for (int q = 0; q < 32; ++q) {
                float4 w = wr[q];
                const int c  = q >> 3;
                const int u0 = (q & 7) * 4;
                wv[c][u0]     += x * w.x;
                wv[c][u0 + 1] += x * w.y;
                wv[c][u0 + 2] += x * w.z;
                wv[c][u0 + 3] += x * w.w;
            }
        }

        // ---- message -> LDS accumulation (ds_add_f32, no global atomics) ----
        const float4 ef = *(const float4*)(edge_feat + (size_t)e * 4);
        const float e0  = ef.x;
        const float e1x = ef.y, e1y = ef.z, e1z = ef.w;

        const float4* xrow4 = (const float4*)(node_feat + (size_t)src * 128);
        float* arow = accum + local * ACC_STRIDE;

        #pragma unroll
        for (int ug = 0; ug < 8; ++ug) {
            const float4 x0v = xrow4[ug];
            const float4 xa  = xrow4[8 + 3 * ug];
            const float4 xb  = xrow4[9 + 3 * ug];
            const float4 xc  = xrow4[10 + 3 * ug];
            const float x0[4]    = {x0v.x, x0v.y, x0v.z, x0v.w};
            const float x1[4][3] = {{xa.x, xa.y, xa.z},
                                    {xa.w, xb.x, xb.y},
                                    {xb.z, xb.w, xc.x},
                                    {xc.y, xc.z, xc.w}};
            #pragma unroll
            for (int q = 0; q < 4; ++q) {
                const int u = ug * 4 + q;
                const float w000 = wv[0][u];
                const float w011 = wv[1][u];
                const float w101 = wv[2][u];
                const float w110 = wv[3][u];
                const float dot = x1[q][0] * e1x + x1[q][1] * e1y + x1[q][2] * e1z;
                const float o0  = S2 * w000 * x0[q] * e0 + S2_3 * w110 * dot;
                atomicAdd(arow + u, o0);
                const float a = S2 * w011 * x0[q];
                const float b = S2 * w101 * e0;
                atomicAdd(arow + 32 + 3 * u + 0, a * e1x + b * x1[q][0]);
                atomicAdd(arow + 32 + 3 * u + 1, a * e1y + b * x1[q][1]);
                atomicAdd(arow + 32 + 3 * u + 2, a * e1z + b * x1[q][2]);
            }
        }
    }
    __syncthreads();

    // ---- writeout: out (pre-filled with self-connection) += accum ----
    for (int i = t; i < NPB * 32; i += 256) {
        const int local = i >> 5;
        const int f4    = i & 31;
        const int n     = node_base + local;
        if (n < N_NODES) {
            float* op = out + (size_t)n * 128 + f4 * 4;
            float4 o = *(float4*)op;
            const float* ar = accum + local * ACC_STRIDE + f4 * 4;
            o.x += ar[0]; o.y += ar[1]; o.z += ar[2]; o.w += ar[3];
            *(float4*)op = o;
        }
    }
}

extern "C" void kernel_launch(void* const* d_in, const int* in_sizes, int n_in,
                              void* d_out, int out_size, void* d_ws, size_t ws_size,
                              hipStream_t stream)
{
    const int*   ei         = (const int*)  d_in[0];
    const float* node_feat  = (const float*)d_in[1];
    const float* edge_feat  = (const float*)d_in[2];
    const float* edge_embed = (const float*)d_in[3];
    const float* fc_w1      = (const float*)d_in[4];
    const float* fc_b1      = (const float*)d_in[5];
    const float* fc_w2      = (const float*)d_in[6];
    const float* fc_b2      = (const float*)d_in[7];
    const float* fc_w3      = (const float*)d_in[8];
    const float* fc_b3      = (const float*)d_in[9];
    const float* sc_w0      = (const float*)d_in[10];
    const float* sc_w1      = (const float*)d_in[11];
    float* out = (float*)d_out;

    // workspace layout (ints): counts | row_ptr | cursor | csr  (~3.7 MB)
    int* ws      = (int*)d_ws;
    int* counts  = ws;             // N_NODES
    int* row_ptr = ws + 51200;     // N_NODES + 1
    int* cursor  = ws + 102400;    // N_NODES
    int* csr     = ws + 153600;    // N_EDGES

    hipMemsetAsync(counts, 0, N_NODES * sizeof(int), stream);

    hist_kernel   <<<N_EDGES / 256, 256, 0, stream>>>(ei, counts);
    scan_kernel   <<<1, 1024, 0, stream>>>(counts, row_ptr, cursor);
    scatter_kernel<<<N_EDGES / 256, 256, 0, stream>>>(ei, cursor, csr);

    // self-connection fully writes d_out
    sc_kernel<<<N_NODES / 8, 256, 0, stream>>>(node_feat, sc_w0, sc_w1, out);

    // per-node-block gather: MLP + message + LDS aggregation, plain += writeout
    const int gblocks = (N_NODES + NPB - 1) / NPB;
    gather_kernel<<<gblocks, 256, 0, stream>>>(ei, row_ptr, csr,
                                               node_feat, edge_feat, edge_embed,
                                               fc_w1, fc_b1, fc_w2, fc_b2, fc_w3, fc_b3,
                                               out);
}

// Round 3
// 1132.728 us; speedup vs baseline: 5.6180x; 2.7978x over previous
//
#include <hip/hip_runtime.h>
#include <hip/hip_bf16.h>

#define N_EDGES 800000
#define N_NODES 50000
#define NPB 32            // nodes per gather block
#define ACC_STRIDE 129    // 128 + 1 pad

#define S2   0.7071067811865475f
#define S2_3 0.4082482904638631f
#define INV_SQRT_MUL 0.17677669529663687f

__device__ __forceinline__ float silu_f(float x) {
    return x / (1.0f + __expf(-x));
}

// ---------------- CSR build: histogram ----------------
__global__ __launch_bounds__(256)
void hist_kernel(const int* __restrict__ ei, int* __restrict__ counts)
{
    const int e = blockIdx.x * 256 + threadIdx.x;
    if (e < N_EDGES) atomicAdd(&counts[ei[N_EDGES + e]], 1);
}

// ---------------- CSR build: single-block scan (exclusive) ----------------
__global__ __launch_bounds__(1024)
void scan_kernel(const int* __restrict__ counts,
                 int* __restrict__ row_ptr,
                 int* __restrict__ cursor)
{
    __shared__ int buf[1024];
    __shared__ int s_carry;
    const int t = threadIdx.x;
    if (t == 0) s_carry = 0;
    __syncthreads();

    for (int base = 0; base < N_NODES; base += 4096) {
        const int idx0 = base + t * 4;
        int v[4];
        #pragma unroll
        for (int k = 0; k < 4; ++k) {
            const int i = idx0 + k;
            v[k] = (i < N_NODES) ? counts[i] : 0;
        }
        const int tsum = v[0] + v[1] + v[2] + v[3];
        buf[t] = tsum;
        __syncthreads();
        for (int off = 1; off < 1024; off <<= 1) {
            const int x = (t >= off) ? buf[t - off] : 0;
            __syncthreads();
            buf[t] += x;
            __syncthreads();
        }
        const int carry = s_carry;
        int excl = carry + buf[t] - tsum;
        #pragma unroll
        for (int k = 0; k < 4; ++k) {
            const int i = idx0 + k;
            if (i < N_NODES) { row_ptr[i] = excl; cursor[i] = excl; }
            excl += v[k];
        }
        const int total = buf[1023];
        __syncthreads();
        if (t == 0) s_carry = carry + total;
        __syncthreads();
    }
    if (t == 0) row_ptr[N_NODES] = s_carry;
}

// ---------------- CSR build: scatter edge ids (packed with local node idx) ----------------
__global__ __launch_bounds__(256)
void scatter_kernel(const int* __restrict__ ei,
                    int* __restrict__ cursor,
                    int* __restrict__ csr)
{
    const int e = blockIdx.x * 256 + threadIdx.x;
    if (e < N_EDGES) {
        const int dst = ei[N_EDGES + e];
        const int pos = atomicAdd(&cursor[dst], 1);
        csr[pos] = e | ((dst & (NPB - 1)) << 20);
    }
}

// ---------------- self-connection kernel: writes (initializes) d_out ----------------
__global__ __launch_bounds__(256)
void sc_kernel(const float* __restrict__ node_feat,
               const float* __restrict__ sc_w0,
               const float* __restrict__ sc_w1,
               float* __restrict__ out)
{
    __shared__ float sw0[1024];
    __shared__ float sw1[1024];
    __shared__ float xrow[256];

    const int t = threadIdx.x;
    ((float4*)sw0)[t] = ((const float4*)sc_w0)[t];
    ((float4*)sw1)[t] = ((const float4*)sc_w1)[t];
    __syncthreads();

    const int half = t >> 7;
    const int c    = t & 127;

    for (int it = 0; it < 4; ++it) {
        const int n = blockIdx.x * 8 + it * 2 + half;
        if (it) __syncthreads();
        xrow[t] = node_feat[(size_t)n * 128 + c];
        __syncthreads();
        const float* xr = xrow + half * 128;

        float acc = 0.0f;
        if (c < 32) {
            const int v = c;
            #pragma unroll
            for (int u = 0; u < 32; ++u) acc += xr[u] * sw0[u * 32 + v];
        } else {
            const int i = c - 32;
            const int v = i / 3;
            const int j = i - 3 * v;
            #pragma unroll
            for (int u = 0; u < 32; ++u) acc += xr[32 + u * 3 + j] * sw1[u * 32 + v];
        }
        out[(size_t)n * 128 + c] = acc * INV_SQRT_MUL;
    }
}

// ---------------- gather kernel: EPT=2, per-u layer-3, LDS aggregation ----------------
__global__ __launch_bounds__(256, 2)
void gather_kernel(const int* __restrict__ ei,
                   const int* __restrict__ row_ptr,
                   const int* __restrict__ csr,
                   const float* __restrict__ node_feat,
                   const float* __restrict__ edge_feat,
                   const float* __restrict__ edge_embed,
                   const float* __restrict__ W1, const float* __restrict__ B1,
                   const float* __restrict__ W2, const float* __restrict__ B2,
                   const float* __restrict__ W3, const float* __restrict__ B3,
                   float* __restrict__ out)
{
    __shared__ float sW1[2048];
    __shared__ float sW2[2048];
    __shared__ float sW3T[4096];   // transposed: sW3T[o*32 + k] = W3[k*128 + o]
    __shared__ float sB1[64];
    __shared__ float sB2[32];
    __shared__ float sB3[128];
    __shared__ float accum[NPB * ACC_STRIDE];

    const int t = threadIdx.x;
    {
        ((float4*)sW1)[t]       = ((const float4*)W1)[t];
        ((float4*)sW1)[t + 256] = ((const float4*)W1)[t + 256];
        ((float4*)sW2)[t]       = ((const float4*)W2)[t];
        ((float4*)sW2)[t + 256] = ((const float4*)W2)[t + 256];
        #pragma unroll
        for (int r = 0; r < 16; ++r) {
            const int idx = t + 256 * r;       // 0..4095
            const int o = idx >> 5, k = idx & 31;
            sW3T[idx] = W3[k * 128 + o];
        }
        if (t < 64)  sB1[t] = B1[t];
        if (t < 32)  sB2[t] = B2[t];
        if (t < 128) sB3[t] = B3[t];
        for (int i = t; i < NPB * ACC_STRIDE; i += 256) accum[i] = 0.0f;
    }
    __syncthreads();

    const int node_base = blockIdx.x * NPB;
    const int nb_end    = (node_base + NPB < N_NODES) ? node_base + NPB : N_NODES;
    const int start     = row_ptr[node_base];
    const int end       = row_ptr[nb_end];

    for (int i = start + 2 * t; i < end; i += 512) {
        const int  entryA = csr[i];
        const bool validB = (i + 1 < end);
        const int  entryB = validB ? csr[i + 1] : entryA;
        const int  eA = entryA & 0xFFFFF,  eB = entryB & 0xFFFFF;
        const int  localA = entryA >> 20,  localB = entryB >> 20;
        const int  srcA = ei[eA],          srcB = ei[eB];

        const float4 efA = *(const float4*)(edge_feat + (size_t)eA * 4);
        float4 efB = *(const float4*)(edge_feat + (size_t)eB * 4);
        if (!validB) { efB.x = 0.0f; efB.y = 0.0f; efB.z = 0.0f; efB.w = 0.0f; }

        // ---- load edge embeddings ----
        float embA[32], embB[32];
        {
            const float4* ea4 = (const float4*)(edge_embed + (size_t)eA * 32);
            const float4* eb4 = (const float4*)(edge_embed + (size_t)eB * 32);
            #pragma unroll
            for (int k = 0; k < 8; ++k) {
                const float4 a = ea4[k], b = eb4[k];
                embA[4 * k] = a.x; embA[4 * k + 1] = a.y; embA[4 * k + 2] = a.z; embA[4 * k + 3] = a.w;
                embB[4 * k] = b.x; embB[4 * k + 1] = b.y; embB[4 * k + 2] = b.z; embB[4 * k + 3] = b.w;
            }
        }

        // ---- layer 1: h1 = silu(emb @ W1 + b1) ----
        float h1A[64], h1B[64];
        #pragma unroll
        for (int o = 0; o < 64; ++o) { const float b = sB1[o]; h1A[o] = b; h1B[o] = b; }
        #pragma unroll
        for (int u = 0; u < 32; ++u) {
            const float xa = embA[u], xb = embB[u];
            const float4* wr = (const float4*)(sW1 + u * 64);
            #pragma unroll
            for (int o4 = 0; o4 < 16; ++o4) {
                const float4 w = wr[o4];
                h1A[4 * o4]     += xa * w.x;  h1B[4 * o4]     += xb * w.x;
                h1A[4 * o4 + 1] += xa * w.y;  h1B[4 * o4 + 1] += xb * w.y;
                h1A[4 * o4 + 2] += xa * w.z;  h1B[4 * o4 + 2] += xb * w.z;
                h1A[4 * o4 + 3] += xa * w.w;  h1B[4 * o4 + 3] += xb * w.w;
            }
        }
        #pragma unroll
        for (int o = 0; o < 64; ++o) { h1A[o] = silu_f(h1A[o]); h1B[o] = silu_f(h1B[o]); }

        // ---- layer 2: h2 = silu(h1 @ W2 + b2) ----
        float h2A[32], h2B[32];
        #pragma unroll
        for (int v = 0; v < 32; ++v) { const float b = sB2[v]; h2A[v] = b; h2B[v] = b; }
        #pragma unroll
        for (int k = 0; k < 64; ++k) {
            const float xa = h1A[k], xb = h1B[k];
            const float4* wr = (const float4*)(sW2 + k * 32);
            #pragma unroll
            for (int v4 = 0; v4 < 8; ++v4) {
                const float4 w = wr[v4];
                h2A[4 * v4]     += xa * w.x;  h2B[4 * v4]     += xb * w.x;
                h2A[4 * v4 + 1] += xa * w.y;  h2B[4 * v4 + 1] += xb * w.y;
                h2A[4 * v4 + 2] += xa * w.z;  h2B[4 * v4 + 2] += xb * w.z;
                h2A[4 * v4 + 3] += xa * w.w;  h2B[4 * v4 + 3] += xb * w.w;
            }
        }
        #pragma unroll
        for (int v = 0; v < 32; ++v) { h2A[v] = silu_f(h2A[v]); h2B[v] = silu_f(h2B[v]); }

        // ---- layer 3 (per-u dots) + message + LDS aggregation ----
        const float e0A = efA.x, e1xA = efA.y, e1yA = efA.z, e1zA = efA.w;
        const float e0B = efB.x, e1xB = efB.y, e1yB = efB.z, e1zB = efB.w;
        const float4* xA4 = (const float4*)(node_feat + (size_t)srcA * 128);
        const float4* xB4 = (const float4*)(node_feat + (size_t)srcB * 128);
        float* arowA = accum + localA * ACC_STRIDE;
        float* arowB = accum + localB * ACC_STRIDE;
        const bool same = (localA == localB);

        #pragma unroll
        for (int ug = 0; ug < 8; ++ug) {
            const float4 x0Av = xA4[ug];
            const float4 xaA  = xA4[8 + 3 * ug];
            const float4 xbA  = xA4[9 + 3 * ug];
            const float4 xcA  = xA4[10 + 3 * ug];
            const float4 x0Bv = xB4[ug];
            const float4 xaB  = xB4[8 + 3 * ug];
            const float4 xbB  = xB4[9 + 3 * ug];
            const float4 xcB  = xB4[10 + 3 * ug];
            const float x0A[4]    = {x0Av.x, x0Av.y, x0Av.z, x0Av.w};
            const float x1A[4][3] = {{xaA.x, xaA.y, xaA.z},
                                     {xaA.w, xbA.x, xbA.y},
                                     {xbA.z, xbA.w, xcA.x},
                                     {xcA.y, xcA.z, xcA.w}};
            const float x0B[4]    = {x0Bv.x, x0Bv.y, x0Bv.z, x0Bv.w};
            const float x1B[4][3] = {{xaB.x, xaB.y, xaB.z},
                                     {xaB.w, xbB.x, xbB.y},
                                     {xbB.z, xbB.w, xcB.x},
                                     {xcB.y, xcB.z, xcB.w}};
            #pragma unroll
            for (int q = 0; q < 4; ++q) {
                const int u = 4 * ug + q;
                float w0A = sB3[u], w1A = sB3[32 + u], w2A = sB3[64 + u], w3A = sB3[96 + u];
                float w0B = w0A, w1B = w1A, w2B = w2A, w3B = w3A;
                const float4* r0 = (const float4*)(sW3T + u * 32);
                const float4* r1 = (const float4*)(sW3T + (32 + u) * 32);
                const float4* r2 = (const float4*)(sW3T + (64 + u) * 32);
                const float4* r3 = (const float4*)(sW3T + (96 + u) * 32);
                #pragma unroll
                for (int k4 = 0; k4 < 8; ++k4) {
                    const float4 c0 = r0[k4], c1 = r1[k4], c2 = r2[k4], c3 = r3[k4];
                    const float a0 = h2A[4 * k4], a1 = h2A[4 * k4 + 1],
                                a2 = h2A[4 * k4 + 2], a3 = h2A[4 * k4 + 3];
                    const float b0 = h2B[4 * k4], b1 = h2B[4 * k4 + 1],
                                b2 = h2B[4 * k4 + 2], b3 = h2B[4 * k4 + 3];
                    w0A += a0 * c0.x + a1 * c0.y + a2 * c0.z + a3 * c0.w;
                    w1A += a0 * c1.x + a1 * c1.y + a2 * c1.z + a3 * c1.w;
                    w2A += a0 * c2.x + a1 * c2.y + a2 * c2.z + a3 * c2.w;
                    w3A += a0 * c3.x + a1 * c3.y + a2 * c3.z + a3 * c3.w;
                    w0B += b0 * c0.x + b1 * c0.y + b2 * c0.z + b3 * c0.w;
                    w1B += b0 * c1.x + b1 * c1.y + b2 * c1.z + b3 * c1.w;
                    w2B += b0 * c2.x + b1 * c2.y + b2 * c2.z + b3 * c2.w;
                    w3B += b0 * c3.x + b1 * c3.y + b2 * c3.z + b3 * c3.w;
                }
                const float dotA = x1A[q][0] * e1xA + x1A[q][1] * e1yA + x1A[q][2] * e1zA;
                const float o0A  = S2 * w0A * x0A[q] * e0A + S2_3 * w3A * dotA;
                const float aA   = S2 * w1A * x0A[q];
                const float bA   = S2 * w2A * e0A;
                const float m1A  = aA * e1xA + bA * x1A[q][0];
                const float m2A  = aA * e1yA + bA * x1A[q][1];
                const float m3A  = aA * e1zA + bA * x1A[q][2];

                const float dotB = x1B[q][0] * e1xB + x1B[q][1] * e1yB + x1B[q][2] * e1zB;
                const float o0B  = S2 * w0B * x0B[q] * e0B + S2_3 * w3B * dotB;
                const float aB   = S2 * w1B * x0B[q];
                const float bB   = S2 * w2B * e0B;
                const float m1B  = aB * e1xB + bB * x1B[q][0];
                const float m2B  = aB * e1yB + bB * x1B[q][1];
                const float m3B  = aB * e1zB + bB * x1B[q][2];

                if (same) {
                    atomicAdd(arowA + u,              o0A + o0B);
                    atomicAdd(arowA + 32 + 3 * u + 0, m1A + m1B);
                    atomicAdd(arowA + 32 + 3 * u + 1, m2A + m2B);
                    atomicAdd(arowA + 32 + 3 * u + 2, m3A + m3B);
                } else {
                    atomicAdd(arowA + u,              o0A);
                    atomicAdd(arowA + 32 + 3 * u + 0, m1A);
                    atomicAdd(arowA + 32 + 3 * u + 1, m2A);
                    atomicAdd(arowA + 32 + 3 * u + 2, m3A);
                    atomicAdd(arowB + u,              o0B);
                    atomicAdd(arowB + 32 + 3 * u + 0, m1B);
                    atomicAdd(arowB + 32 + 3 * u + 1, m2B);
                    atomicAdd(arowB + 32 + 3 * u + 2, m3B);
                }
            }
        }
    }
    __syncthreads();

    // ---- writeout: out (pre-filled with self-connection) += accum ----
    for (int i = t; i < NPB * 32; i += 256) {
        const int local = i >> 5;
        const int f4    = i & 31;
        const int n     = node_base + local;
        if (n < N_NODES) {
            float* op = out + (size_t)n * 128 + f4 * 4;
            float4 o = *(float4*)op;
            const float* ar = accum + local * ACC_STRIDE + f4 * 4;
            o.x += ar[0]; o.y += ar[1]; o.z += ar[2]; o.w += ar[3];
            *(float4*)op = o;
        }
    }
}

extern "C" void kernel_launch(void* const* d_in, const int* in_sizes, int n_in,
                              void* d_out, int out_size, void* d_ws, size_t ws_size,
                              hipStream_t stream)
{
    const int*   ei         = (const int*)  d_in[0];
    const float* node_feat  = (const float*)d_in[1];
    const float* edge_feat  = (const float*)d_in[2];
    const float* edge_embed = (const float*)d_in[3];
    const float* fc_w1      = (const float*)d_in[4];
    const float* fc_b1      = (const float*)d_in[5];
    const float* fc_w2      = (const float*)d_in[6];
    const float* fc_b2      = (const float*)d_in[7];
    const float* fc_w3      = (const float*)d_in[8];
    const float* fc_b3      = (const float*)d_in[9];
    const float* sc_w0      = (const float*)d_in[10];
    const float* sc_w1      = (const float*)d_in[11];
    float* out = (float*)d_out;

    // workspace layout (ints): counts | row_ptr | cursor | csr
    int* ws      = (int*)d_ws;
    int* counts  = ws;
    int* row_ptr = ws + 51200;
    int* cursor  = ws + 102400;
    int* csr     = ws + 153600;

    hipMemsetAsync(counts, 0, N_NODES * sizeof(int), stream);

    hist_kernel   <<<N_EDGES / 256, 256, 0, stream>>>(ei, counts);
    scan_kernel   <<<1, 1024, 0, stream>>>(counts, row_ptr, cursor);
    scatter_kernel<<<N_EDGES / 256, 256, 0, stream>>>(ei, cursor, csr);

    sc_kernel<<<N_NODES / 8, 256, 0, stream>>>(node_feat, sc_w0, sc_w1, out);

    const int gblocks = (N_NODES + NPB - 1) / NPB;
    gather_kernel<<<gblocks, 256, 0, stream>>>(ei, row_ptr, csr,
                                               node_feat, edge_feat, edge_embed,
                                               fc_w1, fc_b1, fc_w2, fc_b2, fc_w3, fc_b3,
                                               out);
}

// Round 4
// 1049.715 us; speedup vs baseline: 6.0623x; 1.0791x over previous
//
#include <hip/hip_runtime.h>
#include <hip/hip_bf16.h>

typedef _Float16 half8 __attribute__((ext_vector_type(8)));
typedef float floatx4 __attribute__((ext_vector_type(4)));

#define N_EDGES 800000
#define N_NODES 50000
#define NPB 32            // nodes per gather block
#define ACC_STRIDE 129    // 128 + 1 pad
#define H1S 72            // halves: 144B row stride (16B shift per row in bank space)
#define H2S 40            // halves: 80B row stride
#define WSTR 68           // floats: 272B row stride

#define S2   0.7071067811865475f
#define S2_3 0.4082482904638631f
#define INV_SQRT_MUL 0.17677669529663687f

__device__ __forceinline__ float silu_f(float x) {
    return x / (1.0f + __expf(-x));
}

// ---------------- CSR build: histogram ----------------
__global__ __launch_bounds__(256)
void hist_kernel(const int* __restrict__ ei, int* __restrict__ counts)
{
    const int e = blockIdx.x * 256 + threadIdx.x;
    if (e < N_EDGES) atomicAdd(&counts[ei[N_EDGES + e]], 1);
}

// ---------------- CSR build: scan (serial-per-thread + one 1024-wide scan) ----------------
__global__ __launch_bounds__(1024)
void scan_kernel(const int* __restrict__ counts,
                 int* __restrict__ row_ptr,
                 int* __restrict__ cursor)
{
    __shared__ int buf[1024];
    const int t = threadIdx.x;
    const int base = t * 49;               // 49*1024 = 50176 >= N_NODES
    int s = 0;
    for (int k = 0; k < 49; ++k) {
        const int i = base + k;
        if (i < N_NODES) s += counts[i];
    }
    buf[t] = s;
    __syncthreads();
    for (int off = 1; off < 1024; off <<= 1) {
        const int x = (t >= off) ? buf[t - off] : 0;
        __syncthreads();
        buf[t] += x;
        __syncthreads();
    }
    int excl = buf[t] - s;
    for (int k = 0; k < 49; ++k) {
        const int i = base + k;
        if (i < N_NODES) {
            row_ptr[i] = excl;
            cursor[i]  = excl;
            excl += counts[i];
        }
    }
    if (t == 1023) row_ptr[N_NODES] = buf[1023];
}

// ---------------- CSR build: scatter edge ids (packed with local node idx) ----------------
__global__ __launch_bounds__(256)
void scatter_kernel(const int* __restrict__ ei,
                    int* __restrict__ cursor,
                    int* __restrict__ csr)
{
    const int e = blockIdx.x * 256 + threadIdx.x;
    if (e < N_EDGES) {
        const int dst = ei[N_EDGES + e];
        const int pos = atomicAdd(&cursor[dst], 1);
        csr[pos] = e | ((dst & (NPB - 1)) << 20);
    }
}

// ---------------- prep: swizzle MLP weights into per-lane MFMA B-fragments (f16) ----------------
// B-frag layout for mfma_f32_16x16x32_f16: lane l holds B[k=(l>>4)*8+j][col=tile*16+(l&15)], j=0..7
__global__ __launch_bounds__(256)
void prep_kernel(const float* __restrict__ W1,
                 const float* __restrict__ W2,
                 const float* __restrict__ W3,
                 _Float16* __restrict__ frags)
{
    const int t = threadIdx.x;
    for (int idx = t; idx < 2048; idx += 256) {            // W1: 4 tiles
        const int j = idx & 7, l = (idx >> 3) & 63, tt = idx >> 9;
        frags[idx] = (_Float16)W1[((l >> 4) * 8 + j) * 64 + tt * 16 + (l & 15)];
    }
    for (int idx = t; idx < 2048; idx += 256) {            // W2: 2 k-chunks x 2 tiles
        const int j = idx & 7, l = (idx >> 3) & 63, tt = (idx >> 9) & 1, kc = idx >> 10;
        frags[2048 + idx] = (_Float16)W2[(kc * 32 + (l >> 4) * 8 + j) * 32 + tt * 16 + (l & 15)];
    }
    for (int idx = t; idx < 4096; idx += 256) {            // W3: 8 tiles
        const int j = idx & 7, l = (idx >> 3) & 63, tt = idx >> 9;
        frags[4096 + idx] = (_Float16)W3[((l >> 4) * 8 + j) * 128 + tt * 16 + (l & 15)];
    }
}

// ---------------- self-connection kernel: writes (initializes) d_out ----------------
__global__ __launch_bounds__(256)
void sc_kernel(const float* __restrict__ node_feat,
               const float* __restrict__ sc_w0,
               const float* __restrict__ sc_w1,
               float* __restrict__ out)
{
    __shared__ float sw0[1024];
    __shared__ float sw1[1024];
    __shared__ float xrow[256];

    const int t = threadIdx.x;
    ((float4*)sw0)[t] = ((const float4*)sc_w0)[t];
    ((float4*)sw1)[t] = ((const float4*)sc_w1)[t];
    __syncthreads();

    const int half = t >> 7;
    const int c    = t & 127;

    for (int it = 0; it < 4; ++it) {
        const int n = blockIdx.x * 8 + it * 2 + half;
        if (it) __syncthreads();
        xrow[t] = node_feat[(size_t)n * 128 + c];
        __syncthreads();
        const float* xr = xrow + half * 128;

        float acc = 0.0f;
        if (c < 32) {
            const int v = c;
            #pragma unroll
            for (int u = 0; u < 32; ++u) acc += xr[u] * sw0[u * 32 + v];
        } else {
            const int i = c - 32;
            const int v = i / 3;
            const int j = i - 3 * v;
            #pragma unroll
            for (int u = 0; u < 32; ++u) acc += xr[32 + u * 3 + j] * sw1[u * 32 + v];
        }
        out[(size_t)n * 128 + c] = acc * INV_SQRT_MUL;
    }
}

// ---------------- gather kernel: MFMA MLP (16 edges/wave/tile) + message + LDS agg ----------------
__global__ __launch_bounds__(256, 2)
void gather_kernel(const int* __restrict__ ei,
                   const int* __restrict__ row_ptr,
                   const int* __restrict__ csr,
                   const float* __restrict__ node_feat,
                   const float* __restrict__ edge_feat,
                   const float* __restrict__ edge_embed,
                   const _Float16* __restrict__ frags,
                   const float* __restrict__ B1,
                   const float* __restrict__ B2,
                   const float* __restrict__ B3,
                   float* __restrict__ out)
{
    __shared__ float    accum[NPB * ACC_STRIDE];   // 16.5 KB
    __shared__ _Float16 H1b[4][16 * H1S];          // 4 x 2304 B
    __shared__ _Float16 H2b[4][16 * H2S];          // 4 x 1280 B
    __shared__ float    Wld[4][16 * WSTR];         // 4 x 4352 B

    const int t  = threadIdx.x;
    const int w  = t >> 6;       // wave id
    const int l  = t & 63;       // lane
    const int lg = l >> 4;       // k-chunk group (0..3)
    const int lr = l & 15;       // row/col-in-tile index

    // ---- loop-invariant weight fragments in registers (56 VGPRs) ----
    const half8* f8 = (const half8*)frags;
    half8 w1f[4], w2f[2][2], w3f[8];
    #pragma unroll
    for (int i = 0; i < 4; ++i) w1f[i] = f8[i * 64 + l];
    #pragma unroll
    for (int kc = 0; kc < 2; ++kc)
        #pragma unroll
        for (int i = 0; i < 2; ++i) w2f[kc][i] = f8[256 + kc * 128 + i * 64 + l];
    #pragma unroll
    for (int i = 0; i < 8; ++i) w3f[i] = f8[512 + i * 64 + l];

    float b1r[4], b2r[2], b3r[8];
    #pragma unroll
    for (int i = 0; i < 4; ++i) b1r[i] = B1[i * 16 + lr];
    #pragma unroll
    for (int i = 0; i < 2; ++i) b2r[i] = B2[i * 16 + lr];
    #pragma unroll
    for (int i = 0; i < 8; ++i) b3r[i] = B3[i * 16 + lr];

    for (int i = t; i < NPB * ACC_STRIDE; i += 256) accum[i] = 0.0f;
    __syncthreads();

    const int node_base = blockIdx.x * NPB;
    const int nb_end    = (node_base + NPB < N_NODES) ? node_base + NPB : N_NODES;
    const int start     = row_ptr[node_base];
    const int end       = row_ptr[nb_end];
    const int cnt       = end - start;

    const floatx4 zero = {0.f, 0.f, 0.f, 0.f};
    _Float16* h1p = H1b[w];
    _Float16* h2p = H2b[w];
    float*    wp  = Wld[w];

    for (int tile = w; tile * 16 < cnt; tile += 4) {
        const int tb = start + tile * 16;

        // MLP edge for this lane's A-frag rows (row = lr)
        const int iM  = tb + lr;
        const int iiM = (iM < end) ? iM : end - 1;
        const int eM  = csr[iiM] & 0xFFFFF;

        // message edge for this lane (4 lanes per edge)
        const int  q    = l & 3;
        const int  edg  = l >> 2;
        const int  iX   = tb + edg;
        const bool vX   = iX < end;
        const int  iiX  = vX ? iX : end - 1;
        const int  entX = csr[iiX];
        const int  eX   = entX & 0xFFFFF;
        const int  locX = entX >> 20;
        const int  srcX = ei[eX];

        float4 efX = {0.f, 0.f, 0.f, 0.f};
        if (vX) efX = *(const float4*)(edge_feat + (size_t)eX * 4);

        // ---- prefetch x[src] for the message phase (hidden under the MLP) ----
        const float* xr = node_feat + (size_t)srcX * 128;
        float4 x0h[2], x1h[2][3];
        #pragma unroll
        for (int h = 0; h < 2; ++h) {
            x0h[h] = *(const float4*)(xr + h * 16 + q * 4);
            const float* xb = xr + 32 + 48 * h + 12 * q;
            x1h[h][0] = *(const float4*)(xb);
            x1h[h][1] = *(const float4*)(xb + 4);
            x1h[h][2] = *(const float4*)(xb + 8);
        }

        // ---- A1 fragment: edge eM's embedding, k-chunk lg ----
        const float* ep = edge_embed + (size_t)eM * 32 + lg * 8;
        const float4 ea = *(const float4*)ep;
        const float4 eb = *(const float4*)(ep + 4);
        half8 a1;
        a1[0] = (_Float16)ea.x; a1[1] = (_Float16)ea.y;
        a1[2] = (_Float16)ea.z; a1[3] = (_Float16)ea.w;
        a1[4] = (_Float16)eb.x; a1[5] = (_Float16)eb.y;
        a1[6] = (_Float16)eb.z; a1[7] = (_Float16)eb.w;

        // ---- layer 1: H1 = silu(E @ W1 + b1), 16x64 ----
        #pragma unroll
        for (int tt = 0; tt < 4; ++tt) {
            floatx4 c = __builtin_amdgcn_mfma_f32_16x16x32_f16(a1, w1f[tt], zero, 0, 0, 0);
            #pragma unroll
            for (int r = 0; r < 4; ++r) {
                const float v = silu_f(c[r] + b1r[tt]);
                h1p[(lg * 4 + r) * H1S + tt * 16 + lr] = (_Float16)v;
            }
        }
        const half8 a2_0 = *(const half8*)&h1p[lr * H1S +      lg * 8];
        const half8 a2_1 = *(const half8*)&h1p[lr * H1S + 32 + lg * 8];

        // ---- layer 2: H2 = silu(H1 @ W2 + b2), 16x32 ----
        #pragma unroll
        for (int tt = 0; tt < 2; ++tt) {
            floatx4 c = __builtin_amdgcn_mfma_f32_16x16x32_f16(a2_0, w2f[0][tt], zero, 0, 0, 0);
            c = __builtin_amdgcn_mfma_f32_16x16x32_f16(a2_1, w2f[1][tt], c, 0, 0, 0);
            #pragma unroll
            for (int r = 0; r < 4; ++r) {
                const float v = silu_f(c[r] + b2r[tt]);
                h2p[(lg * 4 + r) * H2S + tt * 16 + lr] = (_Float16)v;
            }
        }
        const half8 a3 = *(const half8*)&h2p[lr * H2S + lg * 8];

        // ---- layer 3 + message, in 2 halves (u 0..15, 16..31) ----
        float* arow = accum + locX * ACC_STRIDE;
        #pragma unroll
        for (int h = 0; h < 2; ++h) {
            // tiles {h, 2+h, 4+h, 6+h} -> Wld[row][wtype*16 + (col&15)]
            #pragma unroll
            for (int ttt = 0; ttt < 4; ++ttt) {
                const int tt = ttt * 2 + h;
                floatx4 c = __builtin_amdgcn_mfma_f32_16x16x32_f16(a3, w3f[tt], zero, 0, 0, 0);
                #pragma unroll
                for (int r = 0; r < 4; ++r)
                    wp[(lg * 4 + r) * WSTR + ttt * 16 + lr] = c[r] + b3r[tt];
            }

            const float4 w0v = *(const float4*)&wp[edg * WSTR +      q * 4];
            const float4 w1v = *(const float4*)&wp[edg * WSTR + 16 + q * 4];
            const float4 w2v = *(const float4*)&wp[edg * WSTR + 32 + q * 4];
            const float4 w3v = *(const float4*)&wp[edg * WSTR + 48 + q * 4];
            const float wa0[4] = {w0v.x, w0v.y, w0v.z, w0v.w};
            const float wa1[4] = {w1v.x, w1v.y, w1v.z, w1v.w};
            const float wa2[4] = {w2v.x, w2v.y, w2v.z, w2v.w};
            const float wa3[4] = {w3v.x, w3v.y, w3v.z, w3v.w};

            const float e0  = efX.x, e1x = efX.y, e1y = efX.z, e1z = efX.w;
            const float x0a[4] = {x0h[h].x, x0h[h].y, x0h[h].z, x0h[h].w};
            const float xx[12] = {x1h[h][0].x, x1h[h][0].y, x1h[h][0].z, x1h[h][0].w,
                                  x1h[h][1].x, x1h[h][1].y, x1h[h][1].z, x1h[h][1].w,
                                  x1h[h][2].x, x1h[h][2].y, x1h[h][2].z, x1h[h][2].w};
            #pragma unroll
            for (int k = 0; k < 4; ++k) {
                const int u = h * 16 + q * 4 + k;
                const float x1x = xx[3 * k], x1y = xx[3 * k + 1], x1z = xx[3 * k + 2];
                const float dot = x1x * e1x + x1y * e1y + x1z * e1z;
                const float o0  = S2 * wa0[k] * x0a[k] * e0 + S2_3 * wa3[k] * dot;
                const float a   = S2 * wa1[k] * x0a[k];
                const float b   = S2 * wa2[k] * e0;
                atomicAdd(arow + u,              o0);
                atomicAdd(arow + 32 + 3 * u + 0, a * e1x + b * x1x);
                atomicAdd(arow + 32 + 3 * u + 1, a * e1y + b * x1y);
                atomicAdd(arow + 32 + 3 * u + 2, a * e1z + b * x1z);
            }
        }
    }
    __syncthreads();

    // ---- writeout: out (pre-filled with self-connection) += accum ----
    for (int i = t; i < NPB * 32; i += 256) {
        const int local = i >> 5;
        const int f4    = i & 31;
        const int n     = node_base + local;
        if (n < N_NODES) {
            float* op = out + (size_t)n * 128 + f4 * 4;
            float4 o = *(float4*)op;
            const float* ar = accum + local * ACC_STRIDE + f4 * 4;
            o.x += ar[0]; o.y += ar[1]; o.z += ar[2]; o.w += ar[3];
            *(float4*)op = o;
        }
    }
}

extern "C" void kernel_launch(void* const* d_in, const int* in_sizes, int n_in,
                              void* d_out, int out_size, void* d_ws, size_t ws_size,
                              hipStream_t stream)
{
    const int*   ei         = (const int*)  d_in[0];
    const float* node_feat  = (const float*)d_in[1];
    const float* edge_feat  = (const float*)d_in[2];
    const float* edge_embed = (const float*)d_in[3];
    const float* fc_w1      = (const float*)d_in[4];
    const float* fc_b1      = (const float*)d_in[5];
    const float* fc_w2      = (const float*)d_in[6];
    const float* fc_b2      = (const float*)d_in[7];
    const float* fc_w3      = (const float*)d_in[8];
    const float* fc_b3      = (const float*)d_in[9];
    const float* sc_w0      = (const float*)d_in[10];
    const float* sc_w1      = (const float*)d_in[11];
    float* out = (float*)d_out;

    // workspace layout (ints): counts | row_ptr | cursor | csr | frags(f16)
    int* ws      = (int*)d_ws;
    int* counts  = ws;
    int* row_ptr = ws + 51200;
    int* cursor  = ws + 102400;
    int* csr     = ws + 153600;
    _Float16* frags = (_Float16*)(csr + N_EDGES);   // 8192 halves = 16 KB

    hipMemsetAsync(counts, 0, N_NODES * sizeof(int), stream);

    hist_kernel   <<<N_EDGES / 256, 256, 0, stream>>>(ei, counts);
    scan_kernel   <<<1, 1024, 0, stream>>>(counts, row_ptr, cursor);
    scatter_kernel<<<N_EDGES / 256, 256, 0, stream>>>(ei, cursor, csr);
    prep_kernel   <<<1, 256, 0, stream>>>(fc_w1, fc_w2, fc_w3, frags);

    sc_kernel<<<N_NODES / 8, 256, 0, stream>>>(node_feat, sc_w0, sc_w1, out);

    const int gblocks = (N_NODES + NPB - 1) / NPB;
    gather_kernel<<<gblocks, 256, 0, stream>>>(ei, row_ptr, csr,
                                               node_feat, edge_feat, edge_embed,
                                               frags, fc_b1, fc_b2, fc_b3,
                                               out);
}

// Round 6
// 675.680 us; speedup vs baseline: 9.4183x; 1.5536x over previous
//
#include <hip/hip_runtime.h>
#include <hip/hip_bf16.h>

typedef _Float16 half8 __attribute__((ext_vector_type(8)));
typedef _Float16 half4v __attribute__((ext_vector_type(4)));
typedef float floatx4 __attribute__((ext_vector_type(4)));

#define N_EDGES 800000
#define N_NODES 50000
#define NPB 32            // nodes per gather block
#define ACC_STRIDE 129    // fused-fallback accumulator stride
#define H1S 72            // halves: 144B row stride
#define H2S 40            // halves: 80B row stride
#define WSTR 68           // fused fallback: floats, 272B row stride
#define WH 136            // mlp kernel: halves, 272B row stride

#define S2   0.7071067811865475f
#define S2_3 0.4082482904638631f
#define INV_SQRT_MUL 0.17677669529663687f

__device__ __forceinline__ float silu_f(float x) {
    return x / (1.0f + __expf(-x));
}

// ---------------- CSR build: histogram ----------------
__global__ __launch_bounds__(256)
void hist_kernel(const int* __restrict__ ei, int* __restrict__ counts)
{
    const int e = blockIdx.x * 256 + threadIdx.x;
    if (e < N_EDGES) atomicAdd(&counts[ei[N_EDGES + e]], 1);
}

// ---------------- CSR build: scan ----------------
__global__ __launch_bounds__(1024)
void scan_kernel(const int* __restrict__ counts,
                 int* __restrict__ row_ptr,
                 int* __restrict__ cursor)
{
    __shared__ int buf[1024];
    const int t = threadIdx.x;
    const int base = t * 49;               // 49*1024 = 50176 >= N_NODES
    int s = 0;
    for (int k = 0; k < 49; ++k) {
        const int i = base + k;
        if (i < N_NODES) s += counts[i];
    }
    buf[t] = s;
    __syncthreads();
    for (int off = 1; off < 1024; off <<= 1) {
        const int x = (t >= off) ? buf[t - off] : 0;
        __syncthreads();
        buf[t] += x;
        __syncthreads();
    }
    int excl = buf[t] - s;
    for (int k = 0; k < 49; ++k) {
        const int i = base + k;
        if (i < N_NODES) {
            row_ptr[i] = excl;
            cursor[i]  = excl;
            excl += counts[i];
        }
    }
    if (t == 1023) row_ptr[N_NODES] = buf[1023];
}

// ---------------- CSR build: scatter ----------------
__global__ __launch_bounds__(256)
void scatter_kernel(const int* __restrict__ ei,
                    int* __restrict__ cursor,
                    int* __restrict__ csr)
{
    const int e = blockIdx.x * 256 + threadIdx.x;
    if (e < N_EDGES) {
        const int dst = ei[N_EDGES + e];
        const int pos = atomicAdd(&cursor[dst], 1);
        csr[pos] = e | ((dst & (NPB - 1)) << 20);
    }
}

// ---------------- prep: swizzle MLP weights into per-lane MFMA B-fragments (f16) ----------------
// B-frag layout for mfma_f32_16x16x32_f16: lane l holds B[k=(l>>4)*8+j][col=tile*16+(l&15)], j=0..7
__global__ __launch_bounds__(256)
void prep_kernel(const float* __restrict__ W1,
                 const float* __restrict__ W2,
                 const float* __restrict__ W3,
                 _Float16* __restrict__ frags)
{
    const int t = threadIdx.x;
    for (int idx = t; idx < 2048; idx += 256) {            // W1: 4 tiles
        const int j = idx & 7, l = (idx >> 3) & 63, tt = idx >> 9;
        frags[idx] = (_Float16)W1[((l >> 4) * 8 + j) * 64 + tt * 16 + (l & 15)];
    }
    for (int idx = t; idx < 2048; idx += 256) {            // W2: 2 k-chunks x 2 tiles
        const int j = idx & 7, l = (idx >> 3) & 63, tt = (idx >> 9) & 1, kc = idx >> 10;
        frags[2048 + idx] = (_Float16)W2[(kc * 32 + (l >> 4) * 8 + j) * 32 + tt * 16 + (l & 15)];
    }
    for (int idx = t; idx < 4096; idx += 256) {            // W3: 8 tiles
        const int j = idx & 7, l = (idx >> 3) & 63, tt = idx >> 9;
        frags[4096 + idx] = (_Float16)W3[((l >> 4) * 8 + j) * 128 + tt * 16 + (l & 15)];
    }
}

// ---------------- self-connection kernel: writes (initializes) d_out ----------------
__global__ __launch_bounds__(256)
void sc_kernel(const float* __restrict__ node_feat,
               const float* __restrict__ sc_w0,
               const float* __restrict__ sc_w1,
               float* __restrict__ out)
{
    __shared__ float sw0[1024];
    __shared__ float sw1[1024];
    __shared__ float xrow[256];

    const int t = threadIdx.x;
    ((float4*)sw0)[t] = ((const float4*)sc_w0)[t];
    ((float4*)sw1)[t] = ((const float4*)sc_w1)[t];
    __syncthreads();

    const int half = t >> 7;
    const int c    = t & 127;

    for (int it = 0; it < 4; ++it) {
        const int n = blockIdx.x * 8 + it * 2 + half;
        if (it) __syncthreads();
        xrow[t] = node_feat[(size_t)n * 128 + c];
        __syncthreads();
        const float* xr = xrow + half * 128;

        float acc = 0.0f;
        if (c < 32) {
            const int v = c;
            #pragma unroll
            for (int u = 0; u < 32; ++u) acc += xr[u] * sw0[u * 32 + v];
        } else {
            const int i = c - 32;
            const int v = i / 3;
            const int j = i - 3 * v;
            #pragma unroll
            for (int u = 0; u < 32; ++u) acc += xr[32 + u * 3 + j] * sw1[u * 32 + v];
        }
        out[(size_t)n * 128 + c] = acc * INV_SQRT_MUL;
    }
}

// ---------------- mlp kernel: natural-order batch MLP, w -> f16 workspace ----------------
// grid 3125 blocks x 4 waves x 4 tiles x 16 edges = 800000
__global__ __launch_bounds__(256, 4)
void mlp_kernel(const float* __restrict__ edge_embed,
                const _Float16* __restrict__ frags,
                const float* __restrict__ B1,
                const float* __restrict__ B2,
                const float* __restrict__ B3,
                _Float16* __restrict__ w16)
{
    __shared__ _Float16 H1b[4][16 * H1S];
    __shared__ _Float16 H2b[4][16 * H2S];
    __shared__ _Float16 Wf[4][16 * WH];

    const int t  = threadIdx.x;
    const int w  = t >> 6;
    const int l  = t & 63;
    const int lg = l >> 4;
    const int lr = l & 15;

    const half8* f8 = (const half8*)frags;
    half8 w1f[4], w2f[2][2], w3f[8];
    #pragma unroll
    for (int i = 0; i < 4; ++i) w1f[i] = f8[i * 64 + l];
    #pragma unroll
    for (int kc = 0; kc < 2; ++kc)
        #pragma unroll
        for (int i = 0; i < 2; ++i) w2f[kc][i] = f8[256 + kc * 128 + i * 64 + l];
    #pragma unroll
    for (int i = 0; i < 8; ++i) w3f[i] = f8[512 + i * 64 + l];

    float b1r[4], b2r[2], b3r[8];
    #pragma unroll
    for (int i = 0; i < 4; ++i) b1r[i] = B1[i * 16 + lr];
    #pragma unroll
    for (int i = 0; i < 2; ++i) b2r[i] = B2[i * 16 + lr];
    #pragma unroll
    for (int i = 0; i < 8; ++i) b3r[i] = B3[i * 16 + lr];

    const floatx4 zero = {0.f, 0.f, 0.f, 0.f};
    _Float16* h1p = H1b[w];
    _Float16* h2p = H2b[w];
    _Float16* wp  = Wf[w];

    for (int it = 0; it < 4; ++it) {
        const int tile  = (blockIdx.x * 4 + w) * 4 + it;
        const int ebase = tile * 16;

        // A1: lane reads emb[ebase+lr][lg*8 .. +7] (coalesced at line level)
        const float* ep = edge_embed + (size_t)(ebase + lr) * 32 + lg * 8;
        const float4 ea = *(const float4*)ep;
        const float4 eb = *(const float4*)(ep + 4);
        half8 a1;
        a1[0] = (_Float16)ea.x; a1[1] = (_Float16)ea.y;
        a1[2] = (_Float16)ea.z; a1[3] = (_Float16)ea.w;
        a1[4] = (_Float16)eb.x; a1[5] = (_Float16)eb.y;
        a1[6] = (_Float16)eb.z; a1[7] = (_Float16)eb.w;

        // ---- layer 1 ----
        #pragma unroll
        for (int tt = 0; tt < 4; ++tt) {
            floatx4 c = __builtin_amdgcn_mfma_f32_16x16x32_f16(a1, w1f[tt], zero, 0, 0, 0);
            #pragma unroll
            for (int r = 0; r < 4; ++r) {
                const float v = silu_f(c[r] + b1r[tt]);
                h1p[(lg * 4 + r) * H1S + tt * 16 + lr] = (_Float16)v;
            }
        }
        const half8 a2_0 = *(const half8*)&h1p[lr * H1S +      lg * 8];
        const half8 a2_1 = *(const half8*)&h1p[lr * H1S + 32 + lg * 8];

        // ---- layer 2 ----
        #pragma unroll
        for (int tt = 0; tt < 2; ++tt) {
            floatx4 c = __builtin_amdgcn_mfma_f32_16x16x32_f16(a2_0, w2f[0][tt], zero, 0, 0, 0);
            c = __builtin_amdgcn_mfma_f32_16x16x32_f16(a2_1, w2f[1][tt], c, 0, 0, 0);
            #pragma unroll
            for (int r = 0; r < 4; ++r) {
                const float v = silu_f(c[r] + b2r[tt]);
                h2p[(lg * 4 + r) * H2S + tt * 16 + lr] = (_Float16)v;
            }
        }
        const half8 a3 = *(const half8*)&h2p[lr * H2S + lg * 8];

        // ---- layer 3: all 8 tiles -> Wf (f16, bias added) ----
        #pragma unroll
        for (int tt = 0; tt < 8; ++tt) {
            floatx4 c = __builtin_amdgcn_mfma_f32_16x16x32_f16(a3, w3f[tt], zero, 0, 0, 0);
            #pragma unroll
            for (int r = 0; r < 4; ++r)
                wp[(lg * 4 + r) * WH + tt * 16 + lr] = (_Float16)(c[r] + b3r[tt]);
        }

        // ---- readback + coalesced f16 store: lane l -> edge row l>>2, cols (l&3)*32..+31 ----
        {
            const int row = l >> 2;
            const int m   = l & 3;
            const _Float16* src = wp + row * WH + m * 32;
            _Float16* dst = w16 + (size_t)(ebase + row) * 128 + m * 32;
            #pragma unroll
            for (int c4 = 0; c4 < 4; ++c4)
                *(half8*)(dst + c4 * 8) = *(const half8*)(src + c4 * 8);
        }
    }
}

// ---------------- gather2: 8 threads/node, register accumulation, no atomics ----------------
__global__ __launch_bounds__(256, 4)
void gather2_kernel(const int* __restrict__ ei,
                    const int* __restrict__ row_ptr,
                    const int* __restrict__ csr,
                    const float* __restrict__ node_feat,
                    const float* __restrict__ edge_feat,
                    const _Float16* __restrict__ w16,
                    float* __restrict__ out)
{
    const int t     = threadIdx.x;
    const int local = t >> 3;
    const int j     = t & 7;
    const int n     = blockIdx.x * NPB + local;
    const bool valid = (n < N_NODES);

    const int beg = valid ? row_ptr[n]     : 0;
    const int end = valid ? row_ptr[n + 1] : 0;

    float acc0[4]  = {0.f, 0.f, 0.f, 0.f};
    float accm[12] = {0.f};

    #pragma unroll 2
    for (int i = beg; i < end; ++i) {
        const int e   = csr[i] & 0xFFFFF;
        const int src = ei[e];

        const float4 ef = *(const float4*)(edge_feat + (size_t)e * 4);
        const float e0  = ef.x, e1x = ef.y, e1y = ef.z, e1z = ef.w;

        const _Float16* wrow = w16 + (size_t)e * 128 + 4 * j;
        const half4v w0 = *(const half4v*)(wrow);
        const half4v w1 = *(const half4v*)(wrow + 32);
        const half4v w2 = *(const half4v*)(wrow + 64);
        const half4v w3 = *(const half4v*)(wrow + 96);

        const float* xr = node_feat + (size_t)src * 128;
        const float4 x0v = *(const float4*)(xr + 4 * j);
        const float4 xa  = *(const float4*)(xr + 32 + 12 * j);
        const float4 xb  = *(const float4*)(xr + 36 + 12 * j);
        const float4 xc  = *(const float4*)(xr + 40 + 12 * j);
        const float x0[4]  = {x0v.x, x0v.y, x0v.z, x0v.w};
        const float xx[12] = {xa.x, xa.y, xa.z, xa.w,
                              xb.x, xb.y, xb.z, xb.w,
                              xc.x, xc.y, xc.z, xc.w};
        #pragma unroll
        for (int k = 0; k < 4; ++k) {
            const float x1x = xx[3 * k], x1y = xx[3 * k + 1], x1z = xx[3 * k + 2];
            const float dot = x1x * e1x + x1y * e1y + x1z * e1z;
            acc0[k] += S2 * (float)w0[k] * x0[k] * e0 + S2_3 * (float)w3[k] * dot;
            const float a = S2 * (float)w1[k] * x0[k];
            const float b = S2 * (float)w2[k] * e0;
            accm[3 * k + 0] += a * e1x + b * x1x;
            accm[3 * k + 1] += a * e1y + b * x1y;
            accm[3 * k + 2] += a * e1z + b * x1z;
        }
    }

    if (valid) {
        float* op = out + (size_t)n * 128;
        float4 o0 = *(float4*)(op + 4 * j);
        o0.x += acc0[0]; o0.y += acc0[1]; o0.z += acc0[2]; o0.w += acc0[3];
        *(float4*)(op + 4 * j) = o0;

        float* mp = op + 32 + 12 * j;
        float4 m0 = *(float4*)(mp);
        float4 m1 = *(float4*)(mp + 4);
        float4 m2 = *(float4*)(mp + 8);
        m0.x += accm[0]; m0.y += accm[1];  m0.z += accm[2];  m0.w += accm[3];
        m1.x += accm[4]; m1.y += accm[5];  m1.z += accm[6];  m1.w += accm[7];
        m2.x += accm[8]; m2.y += accm[9];  m2.z += accm[10]; m2.w += accm[11];
        *(float4*)(mp)     = m0;
        *(float4*)(mp + 4) = m1;
        *(float4*)(mp + 8) = m2;
    }
}

// ---------------- fused fallback (round-4 gather): used only if ws too small ----------------
__global__ __launch_bounds__(256, 2)
void gather_fused_kernel(const int* __restrict__ ei,
                         const int* __restrict__ row_ptr,
                         const int* __restrict__ csr,
                         const float* __restrict__ node_feat,
                         const float* __restrict__ edge_feat,
                         const float* __restrict__ edge_embed,
                         const _Float16* __restrict__ frags,
                         const float* __restrict__ B1,
                         const float* __restrict__ B2,
                         const float* __restrict__ B3,
                         float* __restrict__ out)
{
    __shared__ float    accum[NPB * ACC_STRIDE];
    __shared__ _Float16 H1b[4][16 * H1S];
    __shared__ _Float16 H2b[4][16 * H2S];
    __shared__ float    Wld[4][16 * WSTR];

    const int t  = threadIdx.x;
    const int w  = t >> 6;
    const int l  = t & 63;
    const int lg = l >> 4;
    const int lr = l & 15;

    const half8* f8 = (const half8*)frags;
    half8 w1f[4], w2f[2][2], w3f[8];
    #pragma unroll
    for (int i = 0; i < 4; ++i) w1f[i] = f8[i * 64 + l];
    #pragma unroll
    for (int kc = 0; kc < 2; ++kc)
        #pragma unroll
        for (int i = 0; i < 2; ++i) w2f[kc][i] = f8[256 + kc * 128 + i * 64 + l];
    #pragma unroll
    for (int i = 0; i < 8; ++i) w3f[i] = f8[512 + i * 64 + l];

    float b1r[4], b2r[2], b3r[8];
    #pragma unroll
    for (int i = 0; i < 4; ++i) b1r[i] = B1[i * 16 + lr];
    #pragma unroll
    for (int i = 0; i < 2; ++i) b2r[i] = B2[i * 16 + lr];
    #pragma unroll
    for (int i = 0; i < 8; ++i) b3r[i] = B3[i * 16 + lr];

    for (int i = t; i < NPB * ACC_STRIDE; i += 256) accum[i] = 0.0f;
    __syncthreads();

    const int node_base = blockIdx.x * NPB;
    const int nb_end    = (node_base + NPB < N_NODES) ? node_base + NPB : N_NODES;
    const int start     = row_ptr[node_base];
    const int end       = row_ptr[nb_end];
    const int cnt       = end - start;

    const floatx4 zero = {0.f, 0.f, 0.f, 0.f};
    _Float16* h1p = H1b[w];
    _Float16* h2p = H2b[w];
    float*    wp  = Wld[w];

    for (int tile = w; tile * 16 < cnt; tile += 4) {
        const int tb = start + tile * 16;
        const int iM  = tb + lr;
        const int iiM = (iM < end) ? iM : end - 1;
        const int eM  = csr[iiM] & 0xFFFFF;

        const int  q    = l & 3;
        const int  edg  = l >> 2;
        const int  iX   = tb + edg;
        const bool vX   = iX < end;
        const int  iiX  = vX ? iX : end - 1;
        const int  entX = csr[iiX];
        const int  eX   = entX & 0xFFFFF;
        const int  locX = entX >> 20;
        const int  srcX = ei[eX];

        float4 efX = {0.f, 0.f, 0.f, 0.f};
        if (vX) efX = *(const float4*)(edge_feat + (size_t)eX * 4);

        const float* xr = node_feat + (size_t)srcX * 128;
        float4 x0h[2], x1h[2][3];
        #pragma unroll
        for (int h = 0; h < 2; ++h) {
            x0h[h] = *(const float4*)(xr + h * 16 + q * 4);
            const float* xb = xr + 32 + 48 * h + 12 * q;
            x1h[h][0] = *(const float4*)(xb);
            x1h[h][1] = *(const float4*)(xb + 4);
            x1h[h][2] = *(const float4*)(xb + 8);
        }

        const float* ep = edge_embed + (size_t)eM * 32 + lg * 8;
        const float4 ea = *(const float4*)ep;
        const float4 eb = *(const float4*)(ep + 4);
        half8 a1;
        a1[0] = (_Float16)ea.x; a1[1] = (_Float16)ea.y;
        a1[2] = (_Float16)ea.z; a1[3] = (_Float16)ea.w;
        a1[4] = (_Float16)eb.x; a1[5] = (_Float16)eb.y;
        a1[6] = (_Float16)eb.z; a1[7] = (_Float16)eb.w;

        #pragma unroll
        for (int tt = 0; tt < 4; ++tt) {
            floatx4 c = __builtin_amdgcn_mfma_f32_16x16x32_f16(a1, w1f[tt], zero, 0, 0, 0);
            #pragma unroll
            for (int r = 0; r < 4; ++r) {
                const float v = silu_f(c[r] + b1r[tt]);
                h1p[(lg * 4 + r) * H1S + tt * 16 + lr] = (_Float16)v;
            }
        }
        const half8 a2_0 = *(const half8*)&h1p[lr * H1S +      lg * 8];
        const half8 a2_1 = *(const half8*)&h1p[lr * H1S + 32 + lg * 8];

        #pragma unroll
        for (int tt = 0; tt < 2; ++tt) {
            floatx4 c = __builtin_amdgcn_mfma_f32_16x16x32_f16(a2_0, w2f[0][tt], zero, 0, 0, 0);
            c = __builtin_amdgcn_mfma_f32_16x16x32_f16(a2_1, w2f[1][tt], c, 0, 0, 0);
            #pragma unroll
            for (int r = 0; r < 4; ++r) {
                const float v = silu_f(c[r] + b2r[tt]);
                h2p[(lg * 4 + r) * H2S + tt * 16 + lr] = (_Float16)v;
            }
        }
        const half8 a3 = *(const half8*)&h2p[lr * H2S + lg * 8];

        float* arow = accum + locX * ACC_STRIDE;
        #pragma unroll
        for (int h = 0; h < 2; ++h) {
            #pragma unroll
            for (int ttt = 0; ttt < 4; ++ttt) {
                const int tt = ttt * 2 + h;
                floatx4 c = __builtin_amdgcn_mfma_f32_16x16x32_f16(a3, w3f[tt], zero, 0, 0, 0);
                #pragma unroll
                for (int r = 0; r < 4; ++r)
                    wp[(lg * 4 + r) * WSTR + ttt * 16 + lr] = c[r] + b3r[tt];
            }

            const float4 w0v = *(const float4*)&wp[edg * WSTR +      q * 4];
            const float4 w1v = *(const float4*)&wp[edg * WSTR + 16 + q * 4];
            const float4 w2v = *(const float4*)&wp[edg * WSTR + 32 + q * 4];
            const float4 w3v = *(const float4*)&wp[edg * WSTR + 48 + q * 4];
            const float wa0[4] = {w0v.x, w0v.y, w0v.z, w0v.w};
            const float wa1[4] = {w1v.x, w1v.y, w1v.z, w1v.w};
            const float wa2[4] = {w2v.x, w2v.y, w2v.z, w2v.w};
            const float wa3[4] = {w3v.x, w3v.y, w3v.z, w3v.w};

            const float e0  = efX.x, e1x = efX.y, e1y = efX.z, e1z = efX.w;
            const float x0a[4] = {x0h[h].x, x0h[h].y, x0h[h].z, x0h[h].w};
            const float xx[12] = {x1h[h][0].x, x1h[h][0].y, x1h[h][0].z, x1h[h][0].w,
                                  x1h[h][1].x, x1h[h][1].y, x1h[h][1].z, x1h[h][1].w,
                                  x1h[h][2].x, x1h[h][2].y, x1h[h][2].z, x1h[h][2].w};
            #pragma unroll
            for (int k = 0; k < 4; ++k) {
                const int u = h * 16 + q * 4 + k;
                const float x1x = xx[3 * k], x1y = xx[3 * k + 1], x1z = xx[3 * k + 2];
                const float dot = x1x * e1x + x1y * e1y + x1z * e1z;
                const float o0  = S2 * wa0[k] * x0a[k] * e0 + S2_3 * wa3[k] * dot;
                const float a   = S2 * wa1[k] * x0a[k];
                const float b   = S2 * wa2[k] * e0;
                atomicAdd(arow + u,              o0);
                atomicAdd(arow + 32 + 3 * u + 0, a * e1x + b * x1x);
                atomicAdd(arow + 32 + 3 * u + 1, a * e1y + b * x1y);
                atomicAdd(arow + 32 + 3 * u + 2, a * e1z + b * x1z);
            }
        }
    }
    __syncthreads();

    for (int i = t; i < NPB * 32; i += 256) {
        const int local = i >> 5;
        const int f4    = i & 31;
        const int n     = node_base + local;
        if (n < N_NODES) {
            float* op = out + (size_t)n * 128 + f4 * 4;
            float4 o = *(float4*)op;
            const float* ar = accum + local * ACC_STRIDE + f4 * 4;
            o.x += ar[0]; o.y += ar[1]; o.z += ar[2]; o.w += ar[3];
            *(float4*)op = o;
        }
    }
}

extern "C" void kernel_launch(void* const* d_in, const int* in_sizes, int n_in,
                              void* d_out, int out_size, void* d_ws, size_t ws_size,
                              hipStream_t stream)
{
    const int*   ei         = (const int*)  d_in[0];
    const float* node_feat  = (const float*)d_in[1];
    const float* edge_feat  = (const float*)d_in[2];
    const float* edge_embed = (const float*)d_in[3];
    const float* fc_w1      = (const float*)d_in[4];
    const float* fc_b1      = (const float*)d_in[5];
    const float* fc_w2      = (const float*)d_in[6];
    const float* fc_b2      = (const float*)d_in[7];
    const float* fc_w3      = (const float*)d_in[8];
    const float* fc_b3      = (const float*)d_in[9];
    const float* sc_w0      = (const float*)d_in[10];
    const float* sc_w1      = (const float*)d_in[11];
    float* out = (float*)d_out;

    // workspace layout (ints): counts | row_ptr | cursor | csr | frags(f16) | w16(f16)
    int* ws      = (int*)d_ws;
    int* counts  = ws;
    int* row_ptr = ws + 51200;
    int* cursor  = ws + 102400;
    int* csr     = ws + 153600;
    _Float16* frags = (_Float16*)(csr + N_EDGES);            // byte 3,814,400; 16 KB
    _Float16* w16   = (_Float16*)((char*)d_ws + 3830784);    // 204.8 MB
    const bool big_ws = (ws_size >= 3830784ULL + 204800000ULL);

    hipMemsetAsync(counts, 0, N_NODES * sizeof(int), stream);

    hist_kernel   <<<N_EDGES / 256, 256, 0, stream>>>(ei, counts);
    scan_kernel   <<<1, 1024, 0, stream>>>(counts, row_ptr, cursor);
    scatter_kernel<<<N_EDGES / 256, 256, 0, stream>>>(ei, cursor, csr);
    prep_kernel   <<<1, 256, 0, stream>>>(fc_w1, fc_w2, fc_w3, frags);

    sc_kernel<<<N_NODES / 8, 256, 0, stream>>>(node_feat, sc_w0, sc_w1, out);

    const int gblocks = (N_NODES + NPB - 1) / NPB;
    if (big_ws) {
        mlp_kernel<<<3125, 256, 0, stream>>>(edge_embed, frags, fc_b1, fc_b2, fc_b3, w16);
        gather2_kernel<<<gblocks, 256, 0, stream>>>(ei, row_ptr, csr,
                                                    node_feat, edge_feat, w16, out);
    } else {
        gather_fused_kernel<<<gblocks, 256, 0, stream>>>(ei, row_ptr, csr,
                                                         node_feat, edge_feat, edge_embed,
                                                         frags, fc_b1, fc_b2, fc_b3,
                                                         out);
    }
}

// Round 7
// 605.126 us; speedup vs baseline: 10.5164x; 1.1166x over previous
//
#include <hip/hip_runtime.h>
#include <hip/hip_bf16.h>

typedef _Float16 half8 __attribute__((ext_vector_type(8)));
typedef _Float16 half4v __attribute__((ext_vector_type(4)));
typedef float floatx4 __attribute__((ext_vector_type(4)));

#define N_EDGES 800000
#define N_NODES 50000
#define NPB 32            // fallback: nodes per gather block (local-bit packing)
#define NPB2 16           // gather2: nodes per block (128 threads)
#define ACC_STRIDE 129    // fused-fallback accumulator stride
#define H1S 72            // halves: 144B row stride
#define H2S 40            // halves: 80B row stride
#define WSTR 68           // fused fallback: floats, 272B row stride
#define WH 136            // mlp kernel: halves, 272B row stride

#define S2   0.7071067811865475f
#define S2_3 0.4082482904638631f
#define INV_SQRT_MUL 0.17677669529663687f

__device__ __forceinline__ float silu_f(float x) {
    return x / (1.0f + __expf(-x));
}

// ---------------- CSR build: histogram ----------------
__global__ __launch_bounds__(256)
void hist_kernel(const int* __restrict__ ei, int* __restrict__ counts)
{
    const int e = blockIdx.x * 256 + threadIdx.x;
    if (e < N_EDGES) atomicAdd(&counts[ei[N_EDGES + e]], 1);
}

// ---------------- CSR build: scan ----------------
__global__ __launch_bounds__(1024)
void scan_kernel(const int* __restrict__ counts,
                 int* __restrict__ row_ptr,
                 int* __restrict__ cursor)
{
    __shared__ int buf[1024];
    const int t = threadIdx.x;
    const int base = t * 49;               // 49*1024 = 50176 >= N_NODES
    int s = 0;
    for (int k = 0; k < 49; ++k) {
        const int i = base + k;
        if (i < N_NODES) s += counts[i];
    }
    buf[t] = s;
    __syncthreads();
    for (int off = 1; off < 1024; off <<= 1) {
        const int x = (t >= off) ? buf[t - off] : 0;
        __syncthreads();
        buf[t] += x;
        __syncthreads();
    }
    int excl = buf[t] - s;
    for (int k = 0; k < 49; ++k) {
        const int i = base + k;
        if (i < N_NODES) {
            row_ptr[i] = excl;
            cursor[i]  = excl;
            excl += counts[i];
        }
    }
    if (t == 1023) row_ptr[N_NODES] = buf[1023];
}

// ---------------- CSR build: scatter (packs edge id + local, and src) ----------------
__global__ __launch_bounds__(256)
void scatter_kernel(const int* __restrict__ ei,
                    int* __restrict__ cursor,
                    int2* __restrict__ csr2)
{
    const int e = blockIdx.x * 256 + threadIdx.x;
    if (e < N_EDGES) {
        const int src = ei[e];
        const int dst = ei[N_EDGES + e];
        const int pos = atomicAdd(&cursor[dst], 1);
        csr2[pos] = make_int2(e | ((dst & (NPB - 1)) << 20), src);
    }
}

// ---------------- prep: swizzle MLP weights into per-lane MFMA B-fragments (f16) ----------------
__global__ __launch_bounds__(256)
void prep_kernel(const float* __restrict__ W1,
                 const float* __restrict__ W2,
                 const float* __restrict__ W3,
                 _Float16* __restrict__ frags)
{
    const int t = threadIdx.x;
    for (int idx = t; idx < 2048; idx += 256) {            // W1: 4 tiles
        const int j = idx & 7, l = (idx >> 3) & 63, tt = idx >> 9;
        frags[idx] = (_Float16)W1[((l >> 4) * 8 + j) * 64 + tt * 16 + (l & 15)];
    }
    for (int idx = t; idx < 2048; idx += 256) {            // W2: 2 k-chunks x 2 tiles
        const int j = idx & 7, l = (idx >> 3) & 63, tt = (idx >> 9) & 1, kc = idx >> 10;
        frags[2048 + idx] = (_Float16)W2[(kc * 32 + (l >> 4) * 8 + j) * 32 + tt * 16 + (l & 15)];
    }
    for (int idx = t; idx < 4096; idx += 256) {            // W3: 8 tiles
        const int j = idx & 7, l = (idx >> 3) & 63, tt = idx >> 9;
        frags[4096 + idx] = (_Float16)W3[((l >> 4) * 8 + j) * 128 + tt * 16 + (l & 15)];
    }
}

// ---------------- self-connection kernel (fallback path only) ----------------
__global__ __launch_bounds__(256)
void sc_kernel(const float* __restrict__ node_feat,
               const float* __restrict__ sc_w0,
               const float* __restrict__ sc_w1,
               float* __restrict__ out)
{
    __shared__ float sw0[1024];
    __shared__ float sw1[1024];
    __shared__ float xrow[256];

    const int t = threadIdx.x;
    ((float4*)sw0)[t] = ((const float4*)sc_w0)[t];
    ((float4*)sw1)[t] = ((const float4*)sc_w1)[t];
    __syncthreads();

    const int half = t >> 7;
    const int c    = t & 127;

    for (int it = 0; it < 4; ++it) {
        const int n = blockIdx.x * 8 + it * 2 + half;
        if (it) __syncthreads();
        xrow[t] = node_feat[(size_t)n * 128 + c];
        __syncthreads();
        const float* xr = xrow + half * 128;

        float acc = 0.0f;
        if (c < 32) {
            const int v = c;
            #pragma unroll
            for (int u = 0; u < 32; ++u) acc += xr[u] * sw0[u * 32 + v];
        } else {
            const int i = c - 32;
            const int v = i / 3;
            const int j = i - 3 * v;
            #pragma unroll
            for (int u = 0; u < 32; ++u) acc += xr[32 + u * 3 + j] * sw1[u * 32 + v];
        }
        out[(size_t)n * 128 + c] = acc * INV_SQRT_MUL;
    }
}

// ---------------- mlp kernel: CSR-ordered batch MLP, w -> f16 workspace (CSR position) ----------------
// grid 3125 blocks x 4 waves x 4 tiles x 16 csr-slots = 800000
__global__ __launch_bounds__(256, 4)
void mlp_kernel(const int2* __restrict__ csr2,
                const float* __restrict__ edge_embed,
                const _Float16* __restrict__ frags,
                const float* __restrict__ B1,
                const float* __restrict__ B2,
                const float* __restrict__ B3,
                _Float16* __restrict__ w16)
{
    __shared__ _Float16 H1b[4][16 * H1S];
    __shared__ _Float16 H2b[4][16 * H2S];
    __shared__ _Float16 Wf[4][16 * WH];

    const int t  = threadIdx.x;
    const int w  = t >> 6;
    const int l  = t & 63;
    const int lg = l >> 4;
    const int lr = l & 15;

    const half8* f8 = (const half8*)frags;
    half8 w1f[4], w2f[2][2], w3f[8];
    #pragma unroll
    for (int i = 0; i < 4; ++i) w1f[i] = f8[i * 64 + l];
    #pragma unroll
    for (int kc = 0; kc < 2; ++kc)
        #pragma unroll
        for (int i = 0; i < 2; ++i) w2f[kc][i] = f8[256 + kc * 128 + i * 64 + l];
    #pragma unroll
    for (int i = 0; i < 8; ++i) w3f[i] = f8[512 + i * 64 + l];

    float b1r[4], b2r[2], b3r[8];
    #pragma unroll
    for (int i = 0; i < 4; ++i) b1r[i] = B1[i * 16 + lr];
    #pragma unroll
    for (int i = 0; i < 2; ++i) b2r[i] = B2[i * 16 + lr];
    #pragma unroll
    for (int i = 0; i < 8; ++i) b3r[i] = B3[i * 16 + lr];

    const floatx4 zero = {0.f, 0.f, 0.f, 0.f};
    _Float16* h1p = H1b[w];
    _Float16* h2p = H2b[w];
    _Float16* wp  = Wf[w];

    for (int it = 0; it < 4; ++it) {
        const int tile = (blockIdx.x * 4 + w) * 4 + it;
        const int tb   = tile * 16;

        // A1: lane's row lr = CSR slot tb+lr -> edge e (gathered emb read)
        const int e = csr2[tb + lr].x & 0xFFFFF;
        const float* ep = edge_embed + (size_t)e * 32 + lg * 8;
        const float4 ea = *(const float4*)ep;
        const float4 eb = *(const float4*)(ep + 4);
        half8 a1;
        a1[0] = (_Float16)ea.x; a1[1] = (_Float16)ea.y;
        a1[2] = (_Float16)ea.z; a1[3] = (_Float16)ea.w;
        a1[4] = (_Float16)eb.x; a1[5] = (_Float16)eb.y;
        a1[6] = (_Float16)eb.z; a1[7] = (_Float16)eb.w;

        // ---- layer 1 ----
        #pragma unroll
        for (int tt = 0; tt < 4; ++tt) {
            floatx4 c = __builtin_amdgcn_mfma_f32_16x16x32_f16(a1, w1f[tt], zero, 0, 0, 0);
            #pragma unroll
            for (int r = 0; r < 4; ++r) {
                const float v = silu_f(c[r] + b1r[tt]);
                h1p[(lg * 4 + r) * H1S + tt * 16 + lr] = (_Float16)v;
            }
        }
        const half8 a2_0 = *(const half8*)&h1p[lr * H1S +      lg * 8];
        const half8 a2_1 = *(const half8*)&h1p[lr * H1S + 32 + lg * 8];

        // ---- layer 2 ----
        #pragma unroll
        for (int tt = 0; tt < 2; ++tt) {
            floatx4 c = __builtin_amdgcn_mfma_f32_16x16x32_f16(a2_0, w2f[0][tt], zero, 0, 0, 0);
            c = __builtin_amdgcn_mfma_f32_16x16x32_f16(a2_1, w2f[1][tt], c, 0, 0, 0);
            #pragma unroll
            for (int r = 0; r < 4; ++r) {
                const float v = silu_f(c[r] + b2r[tt]);
                h2p[(lg * 4 + r) * H2S + tt * 16 + lr] = (_Float16)v;
            }
        }
        const half8 a3 = *(const half8*)&h2p[lr * H2S + lg * 8];

        // ---- layer 3: all 8 tiles -> Wf (f16, bias added) ----
        #pragma unroll
        for (int tt = 0; tt < 8; ++tt) {
            floatx4 c = __builtin_amdgcn_mfma_f32_16x16x32_f16(a3, w3f[tt], zero, 0, 0, 0);
            #pragma unroll
            for (int r = 0; r < 4; ++r)
                wp[(lg * 4 + r) * WH + tt * 16 + lr] = (_Float16)(c[r] + b3r[tt]);
        }

        // ---- readback + coalesced f16 store at CSR position tb+row (sequential) ----
        {
            const int row = l >> 2;
            const int m   = l & 3;
            const _Float16* src = wp + row * WH + m * 32;
            _Float16* dst = w16 + (size_t)(tb + row) * 128 + m * 32;
            #pragma unroll
            for (int c4 = 0; c4 < 4; ++c4)
                *(half8*)(dst + c4 * 8) = *(const half8*)(src + c4 * 8);
        }
    }
}

// ---------------- gather2: 8 threads/node, register accumulation + fused self-connection ----------------
// block 128 = 16 nodes x 8 threads; grid 3125 (covers 50000 exactly)
__global__ __launch_bounds__(128, 4)
void gather2_kernel(const int2* __restrict__ csr2,
                    const int* __restrict__ row_ptr,
                    const float* __restrict__ node_feat,
                    const float* __restrict__ edge_feat,
                    const _Float16* __restrict__ w16,
                    const float* __restrict__ sc_w0,
                    const float* __restrict__ sc_w1,
                    float* __restrict__ out)
{
    __shared__ float sw0[1024];
    __shared__ float sw1[1024];
    __shared__ float xown[NPB2 * 129];     // padded: bank = (local + u) % 32

    const int t     = threadIdx.x;
    const int local = t >> 3;
    const int j     = t & 7;
    const int n     = blockIdx.x * NPB2 + local;   // always < N_NODES (3125*16 = 50000)

    // stage sc weights (512 float4, 128 threads x 4)
    #pragma unroll
    for (int r = 0; r < 2; ++r) {
        ((float4*)sw0)[t + 128 * r] = ((const float4*)sc_w0)[t + 128 * r];
        ((float4*)sw1)[t + 128 * r] = ((const float4*)sc_w1)[t + 128 * r];
    }
    // stage own node rows (each thread: 4 float4 of its node)
    {
        const float4* nr = (const float4*)(node_feat + (size_t)n * 128);
        float* xw = xown + local * 129;
        #pragma unroll
        for (int k = 0; k < 4; ++k) {
            const float4 v = nr[j + 8 * k];
            const int o = 4 * (j + 8 * k);
            xw[o] = v.x; xw[o + 1] = v.y; xw[o + 2] = v.z; xw[o + 3] = v.w;
        }
    }
    __syncthreads();

    const int beg = row_ptr[n];
    const int end = row_ptr[n + 1];

    float acc0[4]  = {0.f, 0.f, 0.f, 0.f};
    float accm[12] = {0.f};

    #pragma unroll 2
    for (int i = beg; i < end; ++i) {
        const int2 c2 = csr2[i];
        const int e   = c2.x & 0xFFFFF;
        const int src = c2.y;

        const float4 ef = *(const float4*)(edge_feat + (size_t)e * 4);
        const float e0  = ef.x, e1x = ef.y, e1y = ef.z, e1z = ef.w;

        const _Float16* wrow = w16 + (size_t)i * 128 + 4 * j;   // sequential stream
        const half4v w0 = *(const half4v*)(wrow);
        const half4v w1 = *(const half4v*)(wrow + 32);
        const half4v w2 = *(const half4v*)(wrow + 64);
        const half4v w3 = *(const half4v*)(wrow + 96);

        const float* xr = node_feat + (size_t)src * 128;
        const float4 x0v = *(const float4*)(xr + 4 * j);
        const float4 xa  = *(const float4*)(xr + 32 + 12 * j);
        const float4 xb  = *(const float4*)(xr + 36 + 12 * j);
        const float4 xc  = *(const float4*)(xr + 40 + 12 * j);
        const float x0[4]  = {x0v.x, x0v.y, x0v.z, x0v.w};
        const float xx[12] = {xa.x, xa.y, xa.z, xa.w,
                              xb.x, xb.y, xb.z, xb.w,
                              xc.x, xc.y, xc.z, xc.w};
        #pragma unroll
        for (int k = 0; k < 4; ++k) {
            const float x1x = xx[3 * k], x1y = xx[3 * k + 1], x1z = xx[3 * k + 2];
            const float dot = x1x * e1x + x1y * e1y + x1z * e1z;
            acc0[k] += S2 * (float)w0[k] * x0[k] * e0 + S2_3 * (float)w3[k] * dot;
            const float a = S2 * (float)w1[k] * x0[k];
            const float b = S2 * (float)w2[k] * e0;
            accm[3 * k + 0] += a * e1x + b * x1x;
            accm[3 * k + 1] += a * e1y + b * x1y;
            accm[3 * k + 2] += a * e1z + b * x1z;
        }
    }

    // ---- fused self-connection: s0[v], s1[v][d] for v in [4j, 4j+4) ----
    float s0[4]  = {0.f, 0.f, 0.f, 0.f};
    float s1[12] = {0.f};
    {
        const float* xr = xown + local * 129;
        #pragma unroll 4
        for (int u = 0; u < 32; ++u) {
            const float a0 = xr[u];
            const float ax = xr[32 + 3 * u], ay = xr[33 + 3 * u], az = xr[34 + 3 * u];
            const float* w0r = sw0 + u * 32 + 4 * j;
            const float* w1r = sw1 + u * 32 + 4 * j;
            #pragma unroll
            for (int k = 0; k < 4; ++k) {
                s0[k] += a0 * w0r[k];
                const float wv = w1r[k];
                s1[3 * k + 0] += ax * wv;
                s1[3 * k + 1] += ay * wv;
                s1[3 * k + 2] += az * wv;
            }
        }
    }

    // ---- writeout: out = agg + sc (full write, no pre-init needed) ----
    {
        float* op = out + (size_t)n * 128;
        float4 o0 = {acc0[0] + s0[0] * INV_SQRT_MUL,
                     acc0[1] + s0[1] * INV_SQRT_MUL,
                     acc0[2] + s0[2] * INV_SQRT_MUL,
                     acc0[3] + s0[3] * INV_SQRT_MUL};
        *(float4*)(op + 4 * j) = o0;

        float* mp = op + 32 + 12 * j;
        float4 m0 = {accm[0] + s1[0] * INV_SQRT_MUL,
                     accm[1] + s1[1] * INV_SQRT_MUL,
                     accm[2] + s1[2] * INV_SQRT_MUL,
                     accm[3] + s1[3] * INV_SQRT_MUL};
        float4 m1 = {accm[4] + s1[4] * INV_SQRT_MUL,
                     accm[5] + s1[5] * INV_SQRT_MUL,
                     accm[6] + s1[6] * INV_SQRT_MUL,
                     accm[7] + s1[7] * INV_SQRT_MUL};
        float4 m2 = {accm[8]  + s1[8]  * INV_SQRT_MUL,
                     accm[9]  + s1[9]  * INV_SQRT_MUL,
                     accm[10] + s1[10] * INV_SQRT_MUL,
                     accm[11] + s1[11] * INV_SQRT_MUL};
        *(float4*)(mp)     = m0;
        *(float4*)(mp + 4) = m1;
        *(float4*)(mp + 8) = m2;
    }
}

// ---------------- fused fallback (round-4 gather): used only if ws too small ----------------
__global__ __launch_bounds__(256, 2)
void gather_fused_kernel(const int* __restrict__ ei,
                         const int* __restrict__ row_ptr,
                         const int2* __restrict__ csr2,
                         const float* __restrict__ node_feat,
                         const float* __restrict__ edge_feat,
                         const float* __restrict__ edge_embed,
                         const _Float16* __restrict__ frags,
                         const float* __restrict__ B1,
                         const float* __restrict__ B2,
                         const float* __restrict__ B3,
                         float* __restrict__ out)
{
    __shared__ float    accum[NPB * ACC_STRIDE];
    __shared__ _Float16 H1b[4][16 * H1S];
    __shared__ _Float16 H2b[4][16 * H2S];
    __shared__ float    Wld[4][16 * WSTR];

    const int t  = threadIdx.x;
    const int w  = t >> 6;
    const int l  = t & 63;
    const int lg = l >> 4;
    const int lr = l & 15;

    const half8* f8 = (const half8*)frags;
    half8 w1f[4], w2f[2][2], w3f[8];
    #pragma unroll
    for (int i = 0; i < 4; ++i) w1f[i] = f8[i * 64 + l];
    #pragma unroll
    for (int kc = 0; kc < 2; ++kc)
        #pragma unroll
        for (int i = 0; i < 2; ++i) w2f[kc][i] = f8[256 + kc * 128 + i * 64 + l];
    #pragma unroll
    for (int i = 0; i < 8; ++i) w3f[i] = f8[512 + i * 64 + l];

    float b1r[4], b2r[2], b3r[8];
    #pragma unroll
    for (int i = 0; i < 4; ++i) b1r[i] = B1[i * 16 + lr];
    #pragma unroll
    for (int i = 0; i < 2; ++i) b2r[i] = B2[i * 16 + lr];
    #pragma unroll
    for (int i = 0; i < 8; ++i) b3r[i] = B3[i * 16 + lr];

    for (int i = t; i < NPB * ACC_STRIDE; i += 256) accum[i] = 0.0f;
    __syncthreads();

    const int node_base = blockIdx.x * NPB;
    const int nb_end    = (node_base + NPB < N_NODES) ? node_base + NPB : N_NODES;
    const int start     = row_ptr[node_base];
    const int end       = row_ptr[nb_end];
    const int cnt       = end - start;

    const floatx4 zero = {0.f, 0.f, 0.f, 0.f};
    _Float16* h1p = H1b[w];
    _Float16* h2p = H2b[w];
    float*    wp  = Wld[w];

    for (int tile = w; tile * 16 < cnt; tile += 4) {
        const int tb = start + tile * 16;
        const int iM  = tb + lr;
        const int iiM = (iM < end) ? iM : end - 1;
        const int eM  = csr2[iiM].x & 0xFFFFF;

        const int  q    = l & 3;
        const int  edg  = l >> 2;
        const int  iX   = tb + edg;
        const bool vX   = iX < end;
        const int  iiX  = vX ? iX : end - 1;
        const int2 enX  = csr2[iiX];
        const int  eX   = enX.x & 0xFFFFF;
        const int  locX = (enX.x >> 20) & (NPB - 1);
        const int  srcX = enX.y;

        float4 efX = {0.f, 0.f, 0.f, 0.f};
        if (vX) efX = *(const float4*)(edge_feat + (size_t)eX * 4);

        const float* xr = node_feat + (size_t)srcX * 128;
        float4 x0h[2], x1h[2][3];
        #pragma unroll
        for (int h = 0; h < 2; ++h) {
            x0h[h] = *(const float4*)(xr + h * 16 + q * 4);
            const float* xb = xr + 32 + 48 * h + 12 * q;
            x1h[h][0] = *(const float4*)(xb);
            x1h[h][1] = *(const float4*)(xb + 4);
            x1h[h][2] = *(const float4*)(xb + 8);
        }

        const float* ep = edge_embed + (size_t)eM * 32 + lg * 8;
        const float4 ea = *(const float4*)ep;
        const float4 eb = *(const float4*)(ep + 4);
        half8 a1;
        a1[0] = (_Float16)ea.x; a1[1] = (_Float16)ea.y;
        a1[2] = (_Float16)ea.z; a1[3] = (_Float16)ea.w;
        a1[4] = (_Float16)eb.x; a1[5] = (_Float16)eb.y;
        a1[6] = (_Float16)eb.z; a1[7] = (_Float16)eb.w;

        #pragma unroll
        for (int tt = 0; tt < 4; ++tt) {
            floatx4 c = __builtin_amdgcn_mfma_f32_16x16x32_f16(a1, w1f[tt], zero, 0, 0, 0);
            #pragma unroll
            for (int r = 0; r < 4; ++r) {
                const float v = silu_f(c[r] + b1r[tt]);
                h1p[(lg * 4 + r) * H1S + tt * 16 + lr] = (_Float16)v;
            }
        }
        const half8 a2_0 = *(const half8*)&h1p[lr * H1S +      lg * 8];
        const half8 a2_1 = *(const half8*)&h1p[lr * H1S + 32 + lg * 8];

        #pragma unroll
        for (int tt = 0; tt < 2; ++tt) {
            floatx4 c = __builtin_amdgcn_mfma_f32_16x16x32_f16(a2_0, w2f[0][tt], zero, 0, 0, 0);
            c = __builtin_amdgcn_mfma_f32_16x16x32_f16(a2_1, w2f[1][tt], c, 0, 0, 0);
            #pragma unroll
            for (int r = 0; r < 4; ++r) {
                const float v = silu_f(c[r] + b2r[tt]);
                h2p[(lg * 4 + r) * H2S + tt * 16 + lr] = (_Float16)v;
            }
        }
        const half8 a3 = *(const half8*)&h2p[lr * H2S + lg * 8];

        float* arow = accum + locX * ACC_STRIDE;
        #pragma unroll
        for (int h = 0; h < 2; ++h) {
            #pragma unroll
            for (int ttt = 0; ttt < 4; ++ttt) {
                const int tt = ttt * 2 + h;
                floatx4 c = __builtin_amdgcn_mfma_f32_16x16x32_f16(a3, w3f[tt], zero, 0, 0, 0);
                #pragma unroll
                for (int r = 0; r < 4; ++r)
                    wp[(lg * 4 + r) * WSTR + ttt * 16 + lr] = c[r] + b3r[tt];
            }

            const float4 w0v = *(const float4*)&wp[edg * WSTR +      q * 4];
            const float4 w1v = *(const float4*)&wp[edg * WSTR + 16 + q * 4];
            const float4 w2v = *(const float4*)&wp[edg * WSTR + 32 + q * 4];
            const float4 w3v = *(const float4*)&wp[edg * WSTR + 48 + q * 4];
            const float wa0[4] = {w0v.x, w0v.y, w0v.z, w0v.w};
            const float wa1[4] = {w1v.x, w1v.y, w1v.z, w1v.w};
            const float wa2[4] = {w2v.x, w2v.y, w2v.z, w2v.w};
            const float wa3[4] = {w3v.x, w3v.y, w3v.z, w3v.w};

            const float e0  = efX.x, e1x = efX.y, e1y = efX.z, e1z = efX.w;
            const float x0a[4] = {x0h[h].x, x0h[h].y, x0h[h].z, x0h[h].w};
            const float xx[12] = {x1h[h][0].x, x1h[h][0].y, x1h[h][0].z, x1h[h][0].w,
                                  x1h[h][1].x, x1h[h][1].y, x1h[h][1].z, x1h[h][1].w,
                                  x1h[h][2].x, x1h[h][2].y, x1h[h][2].z, x1h[h][2].w};
            #pragma unroll
            for (int k = 0; k < 4; ++k) {
                const int u = h * 16 + q * 4 + k;
                const float x1x = xx[3 * k], x1y = xx[3 * k + 1], x1z = xx[3 * k + 2];
                const float dot = x1x * e1x + x1y * e1y + x1z * e1z;
                const float o0  = S2 * wa0[k] * x0a[k] * e0 + S2_3 * wa3[k] * dot;
                const float a   = S2 * wa1[k] * x0a[k];
                const float b   = S2 * wa2[k] * e0;
                atomicAdd(arow + u,              o0);
                atomicAdd(arow + 32 + 3 * u + 0, a * e1x + b * x1x);
                atomicAdd(arow + 32 + 3 * u + 1, a * e1y + b * x1y);
                atomicAdd(arow + 32 + 3 * u + 2, a * e1z + b * x1z);
            }
        }
    }
    __syncthreads();

    for (int i = t; i < NPB * 32; i += 256) {
        const int local = i >> 5;
        const int f4    = i & 31;
        const int n     = node_base + local;
        if (n < N_NODES) {
            float* op = out + (size_t)n * 128 + f4 * 4;
            float4 o = *(float4*)op;
            const float* ar = accum + local * ACC_STRIDE + f4 * 4;
            o.x += ar[0]; o.y += ar[1]; o.z += ar[2]; o.w += ar[3];
            *(float4*)op = o;
        }
    }
}

extern "C" void kernel_launch(void* const* d_in, const int* in_sizes, int n_in,
                              void* d_out, int out_size, void* d_ws, size_t ws_size,
                              hipStream_t stream)
{
    const int*   ei         = (const int*)  d_in[0];
    const float* node_feat  = (const float*)d_in[1];
    const float* edge_feat  = (const float*)d_in[2];
    const float* edge_embed = (const float*)d_in[3];
    const float* fc_w1      = (const float*)d_in[4];
    const float* fc_b1      = (const float*)d_in[5];
    const float* fc_w2      = (const float*)d_in[6];
    const float* fc_b2      = (const float*)d_in[7];
    const float* fc_w3      = (const float*)d_in[8];
    const float* fc_b3      = (const float*)d_in[9];
    const float* sc_w0      = (const float*)d_in[10];
    const float* sc_w1      = (const float*)d_in[11];
    float* out = (float*)d_out;

    // workspace layout: counts | row_ptr | cursor | csr2(int2) | frags(f16) | w16(f16)
    int*  ws      = (int*)d_ws;
    int*  counts  = ws;                                       // N_NODES
    int*  row_ptr = ws + 51200;                               // N_NODES+1
    int*  cursor  = ws + 102400;                              // N_NODES
    int2* csr2    = (int2*)(ws + 153600);                     // byte 614400, 6.4 MB
    _Float16* frags = (_Float16*)((char*)d_ws + 7014400);     // 16 KB
    _Float16* w16   = (_Float16*)((char*)d_ws + 7030784);     // 204.8 MB
    const bool big_ws = (ws_size >= 7030784ULL + 204800000ULL);

    hipMemsetAsync(counts, 0, N_NODES * sizeof(int), stream);

    hist_kernel   <<<N_EDGES / 256, 256, 0, stream>>>(ei, counts);
    scan_kernel   <<<1, 1024, 0, stream>>>(counts, row_ptr, cursor);
    scatter_kernel<<<N_EDGES / 256, 256, 0, stream>>>(ei, cursor, csr2);
    prep_kernel   <<<1, 256, 0, stream>>>(fc_w1, fc_w2, fc_w3, frags);

    if (big_ws) {
        mlp_kernel<<<3125, 256, 0, stream>>>(csr2, edge_embed, frags, fc_b1, fc_b2, fc_b3, w16);
        gather2_kernel<<<N_NODES / NPB2, 128, 0, stream>>>(csr2, row_ptr,
                                                           node_feat, edge_feat, w16,
                                                           sc_w0, sc_w1, out);
    } else {
        sc_kernel<<<N_NODES / 8, 256, 0, stream>>>(node_feat, sc_w0, sc_w1, out);
        gather_fused_kernel<<<(N_NODES + NPB - 1) / NPB, 256, 0, stream>>>(
            ei, row_ptr, csr2, node_feat, edge_feat, edge_embed,
            frags, fc_b1, fc_b2, fc_b3, out);
    }
}

// Round 8
// 471.863 us; speedup vs baseline: 13.4864x; 1.2824x over previous
//
#include <hip/hip_runtime.h>
#include <hip/hip_bf16.h>

typedef _Float16 half8 __attribute__((ext_vector_type(8)));
typedef _Float16 half4v __attribute__((ext_vector_type(4)));
typedef float floatx4 __attribute__((ext_vector_type(4)));

#define N_EDGES 800000
#define N_NODES 50000
#define NPB 32            // fallback: nodes per gather block (local-bit packing)
#define NPB2 16           // gather2: nodes per block (128 threads)
#define NB_SCAN 196       // ceil(N_NODES / 256)
#define ACC_STRIDE 129    // fused-fallback accumulator stride
#define H1S 72            // halves: 144B row stride
#define H2S 40            // halves: 80B row stride
#define WSTR 68           // fused fallback: floats, 272B row stride
#define WH 136            // mlp kernel: halves, 272B row stride

#define S2   0.7071067811865475f
#define S2_3 0.4082482904638631f
#define INV_SQRT_MUL 0.17677669529663687f

__device__ __forceinline__ float silu_f(float x) {
    return x / (1.0f + __expf(-x));
}

// ---------------- CSR build: histogram (int4-vectorized) ----------------
__global__ __launch_bounds__(256)
void hist_kernel(const int* __restrict__ ei, int* __restrict__ counts)
{
    const int e4 = (blockIdx.x * 256 + threadIdx.x) * 4;
    if (e4 < N_EDGES) {   // N_EDGES % 4 == 0
        const int4 d = *(const int4*)(ei + N_EDGES + e4);
        atomicAdd(&counts[d.x], 1);
        atomicAdd(&counts[d.y], 1);
        atomicAdd(&counts[d.z], 1);
        atomicAdd(&counts[d.w], 1);
    }
}

// ---------------- CSR build: stage 1 — per-block scan + block sums ----------------
__global__ __launch_bounds__(256)
void bsum_kernel(const int* __restrict__ counts,
                 int* __restrict__ cursor,   // receives within-block exclusive prefix
                 int* __restrict__ bsum)
{
    __shared__ int buf[256];
    const int t = threadIdx.x;
    const int i = blockIdx.x * 256 + t;
    const int c = (i < N_NODES) ? counts[i] : 0;
    buf[t] = c;
    __syncthreads();
    #pragma unroll
    for (int off = 1; off < 256; off <<= 1) {
        const int x = (t >= off) ? buf[t - off] : 0;
        __syncthreads();
        buf[t] += x;
        __syncthreads();
    }
    if (i < N_NODES) cursor[i] = buf[t] - c;   // exclusive within block
    if (t == 255) bsum[blockIdx.x] = buf[255];
}

// ---------------- CSR build: stage 2 — scan block sums (block 0) + weight prep (block 1) ----------------
__global__ __launch_bounds__(256)
void scan_sums_kernel(const int* __restrict__ bsum,
                      int* __restrict__ boff,
                      int* __restrict__ row_ptr,
                      const float* __restrict__ W1,
                      const float* __restrict__ W2,
                      const float* __restrict__ W3,
                      _Float16* __restrict__ frags)
{
    const int t = threadIdx.x;
    if (blockIdx.x == 0) {
        __shared__ int buf[256];
        const int v = (t < NB_SCAN) ? bsum[t] : 0;
        buf[t] = v;
        __syncthreads();
        #pragma unroll
        for (int off = 1; off < 256; off <<= 1) {
            const int x = (t >= off) ? buf[t - off] : 0;
            __syncthreads();
            buf[t] += x;
            __syncthreads();
        }
        if (t < NB_SCAN) boff[t] = buf[t] - v;   // exclusive
        if (t == 0) row_ptr[N_NODES] = N_EDGES;
    } else {
        // weight prep: swizzle into per-lane MFMA B-fragments (f16)
        for (int idx = t; idx < 2048; idx += 256) {            // W1: 4 tiles
            const int j = idx & 7, l = (idx >> 3) & 63, tt = idx >> 9;
            frags[idx] = (_Float16)W1[((l >> 4) * 8 + j) * 64 + tt * 16 + (l & 15)];
        }
        for (int idx = t; idx < 2048; idx += 256) {            // W2: 2 k-chunks x 2 tiles
            const int j = idx & 7, l = (idx >> 3) & 63, tt = (idx >> 9) & 1, kc = idx >> 10;
            frags[2048 + idx] = (_Float16)W2[(kc * 32 + (l >> 4) * 8 + j) * 32 + tt * 16 + (l & 15)];
        }
        for (int idx = t; idx < 4096; idx += 256) {            // W3: 8 tiles
            const int j = idx & 7, l = (idx >> 3) & 63, tt = idx >> 9;
            frags[4096 + idx] = (_Float16)W3[((l >> 4) * 8 + j) * 128 + tt * 16 + (l & 15)];
        }
    }
}

// ---------------- CSR build: stage 3 — apply block offsets ----------------
__global__ __launch_bounds__(256)
void apply_kernel(const int* __restrict__ boff,
                  int* __restrict__ cursor,
                  int* __restrict__ row_ptr)
{
    const int i = blockIdx.x * 256 + threadIdx.x;
    if (i < N_NODES) {
        const int v = cursor[i] + boff[blockIdx.x];
        row_ptr[i] = v;
        cursor[i]  = v;
    }
}

// ---------------- CSR build: scatter (packs edge id + local, and src) ----------------
__global__ __launch_bounds__(256)
void scatter_kernel(const int* __restrict__ ei,
                    int* __restrict__ cursor,
                    int2* __restrict__ csr2)
{
    const int e = blockIdx.x * 256 + threadIdx.x;
    if (e < N_EDGES) {
        const int src = ei[e];
        const int dst = ei[N_EDGES + e];
        const int pos = atomicAdd(&cursor[dst], 1);
        csr2[pos] = make_int2(e | ((dst & (NPB - 1)) << 20), src);
    }
}

// ---------------- self-connection kernel (fallback path only) ----------------
__global__ __launch_bounds__(256)
void sc_kernel(const float* __restrict__ node_feat,
               const float* __restrict__ sc_w0,
               const float* __restrict__ sc_w1,
               float* __restrict__ out)
{
    __shared__ float sw0[1024];
    __shared__ float sw1[1024];
    __shared__ float xrow[256];

    const int t = threadIdx.x;
    ((float4*)sw0)[t] = ((const float4*)sc_w0)[t];
    ((float4*)sw1)[t] = ((const float4*)sc_w1)[t];
    __syncthreads();

    const int half = t >> 7;
    const int c    = t & 127;

    for (int it = 0; it < 4; ++it) {
        const int n = blockIdx.x * 8 + it * 2 + half;
        if (it) __syncthreads();
        xrow[t] = node_feat[(size_t)n * 128 + c];
        __syncthreads();
        const float* xr = xrow + half * 128;

        float acc = 0.0f;
        if (c < 32) {
            const int v = c;
            #pragma unroll
            for (int u = 0; u < 32; ++u) acc += xr[u] * sw0[u * 32 + v];
        } else {
            const int i = c - 32;
            const int v = i / 3;
            const int j = i - 3 * v;
            #pragma unroll
            for (int u = 0; u < 32; ++u) acc += xr[32 + u * 3 + j] * sw1[u * 32 + v];
        }
        out[(size_t)n * 128 + c] = acc * INV_SQRT_MUL;
    }
}

// ---------------- mlp kernel: CSR-ordered batch MLP, gathers hoisted, w -> f16 ws ----------------
// grid 3125 blocks x 4 waves x 4 tiles x 16 csr-slots = 800000
__global__ __launch_bounds__(256, 4)
void mlp_kernel(const int2* __restrict__ csr2,
                const float* __restrict__ edge_embed,
                const _Float16* __restrict__ frags,
                const float* __restrict__ B1,
                const float* __restrict__ B2,
                const float* __restrict__ B3,
                _Float16* __restrict__ w16)
{
    __shared__ _Float16 H1b[4][16 * H1S];
    __shared__ _Float16 H2b[4][16 * H2S];
    __shared__ _Float16 Wf[4][16 * WH];

    const int t  = threadIdx.x;
    const int w  = t >> 6;
    const int l  = t & 63;
    const int lg = l >> 4;
    const int lr = l & 15;

    const half8* f8 = (const half8*)frags;
    half8 w1f[4], w2f[2][2], w3f[8];
    #pragma unroll
    for (int i = 0; i < 4; ++i) w1f[i] = f8[i * 64 + l];
    #pragma unroll
    for (int kc = 0; kc < 2; ++kc)
        #pragma unroll
        for (int i = 0; i < 2; ++i) w2f[kc][i] = f8[256 + kc * 128 + i * 64 + l];
    #pragma unroll
    for (int i = 0; i < 8; ++i) w3f[i] = f8[512 + i * 64 + l];

    float b1r[4], b2r[2], b3r[8];
    #pragma unroll
    for (int i = 0; i < 4; ++i) b1r[i] = B1[i * 16 + lr];
    #pragma unroll
    for (int i = 0; i < 2; ++i) b2r[i] = B2[i * 16 + lr];
    #pragma unroll
    for (int i = 0; i < 8; ++i) b3r[i] = B3[i * 16 + lr];

    const floatx4 zero = {0.f, 0.f, 0.f, 0.f};
    _Float16* h1p = H1b[w];
    _Float16* h2p = H2b[w];
    _Float16* wp  = Wf[w];

    // ---- hoisted gathers: all 4 tiles' csr slots + embeddings up front ----
    const int slot0 = (blockIdx.x * 4 + w) * 64 + lr;   // CSR slot of this lane's row, tile 0
    int eArr[4];
    #pragma unroll
    for (int it = 0; it < 4; ++it) eArr[it] = csr2[slot0 + it * 16].x & 0xFFFFF;

    half8 a1f[4];
    #pragma unroll
    for (int it = 0; it < 4; ++it) {
        const float* ep = edge_embed + (size_t)eArr[it] * 32 + lg * 8;
        const float4 ea = *(const float4*)ep;
        const float4 eb = *(const float4*)(ep + 4);
        half8 a1;
        a1[0] = (_Float16)ea.x; a1[1] = (_Float16)ea.y;
        a1[2] = (_Float16)ea.z; a1[3] = (_Float16)ea.w;
        a1[4] = (_Float16)eb.x; a1[5] = (_Float16)eb.y;
        a1[6] = (_Float16)eb.z; a1[7] = (_Float16)eb.w;
        a1f[it] = a1;
    }

    #pragma unroll
    for (int it = 0; it < 4; ++it) {
        const int tb = (blockIdx.x * 4 + w) * 64 + it * 16;

        // ---- layer 1 ----
        #pragma unroll
        for (int tt = 0; tt < 4; ++tt) {
            floatx4 c = __builtin_amdgcn_mfma_f32_16x16x32_f16(a1f[it], w1f[tt], zero, 0, 0, 0);
            #pragma unroll
            for (int r = 0; r < 4; ++r) {
                const float v = silu_f(c[r] + b1r[tt]);
                h1p[(lg * 4 + r) * H1S + tt * 16 + lr] = (_Float16)v;
            }
        }
        const half8 a2_0 = *(const half8*)&h1p[lr * H1S +      lg * 8];
        const half8 a2_1 = *(const half8*)&h1p[lr * H1S + 32 + lg * 8];

        // ---- layer 2 ----
        #pragma unroll
        for (int tt = 0; tt < 2; ++tt) {
            floatx4 c = __builtin_amdgcn_mfma_f32_16x16x32_f16(a2_0, w2f[0][tt], zero, 0, 0, 0);
            c = __builtin_amdgcn_mfma_f32_16x16x32_f16(a2_1, w2f[1][tt], c, 0, 0, 0);
            #pragma unroll
            for (int r = 0; r < 4; ++r) {
                const float v = silu_f(c[r] + b2r[tt]);
                h2p[(lg * 4 + r) * H2S + tt * 16 + lr] = (_Float16)v;
            }
        }
        const half8 a3 = *(const half8*)&h2p[lr * H2S + lg * 8];

        // ---- layer 3: all 8 tiles -> Wf (f16, bias added) ----
        #pragma unroll
        for (int tt = 0; tt < 8; ++tt) {
            floatx4 c = __builtin_amdgcn_mfma_f32_16x16x32_f16(a3, w3f[tt], zero, 0, 0, 0);
            #pragma unroll
            for (int r = 0; r < 4; ++r)
                wp[(lg * 4 + r) * WH + tt * 16 + lr] = (_Float16)(c[r] + b3r[tt]);
        }

        // ---- readback + coalesced f16 store at CSR position tb+row (sequential) ----
        {
            const int row = l >> 2;
            const int m   = l & 3;
            const _Float16* src = wp + row * WH + m * 32;
            _Float16* dst = w16 + (size_t)(tb + row) * 128 + m * 32;
            #pragma unroll
            for (int c4 = 0; c4 < 4; ++c4)
                *(half8*)(dst + c4 * 8) = *(const half8*)(src + c4 * 8);
        }
    }
}

// ---------------- gather2: 8 threads/node, register accumulation + fused self-connection ----------------
// block 128 = 16 nodes x 8 threads; grid 3125 (covers 50000 exactly)
__global__ __launch_bounds__(128, 4)
void gather2_kernel(const int2* __restrict__ csr2,
                    const int* __restrict__ row_ptr,
                    const float* __restrict__ node_feat,
                    const float* __restrict__ edge_feat,
                    const _Float16* __restrict__ w16,
                    const float* __restrict__ sc_w0,
                    const float* __restrict__ sc_w1,
                    float* __restrict__ out)
{
    __shared__ float sw0[1024];
    __shared__ float sw1[1024];
    __shared__ float xown[NPB2 * 129];

    const int t     = threadIdx.x;
    const int local = t >> 3;
    const int j     = t & 7;
    const int n     = blockIdx.x * NPB2 + local;   // always < N_NODES

    #pragma unroll
    for (int r = 0; r < 2; ++r) {
        ((float4*)sw0)[t + 128 * r] = ((const float4*)sc_w0)[t + 128 * r];
        ((float4*)sw1)[t + 128 * r] = ((const float4*)sc_w1)[t + 128 * r];
    }
    {
        const float4* nr = (const float4*)(node_feat + (size_t)n * 128);
        float* xw = xown + local * 129;
        #pragma unroll
        for (int k = 0; k < 4; ++k) {
            const float4 v = nr[j + 8 * k];
            const int o = 4 * (j + 8 * k);
            xw[o] = v.x; xw[o + 1] = v.y; xw[o + 2] = v.z; xw[o + 3] = v.w;
        }
    }
    __syncthreads();

    const int beg = row_ptr[n];
    const int end = row_ptr[n + 1];

    float acc0[4]  = {0.f, 0.f, 0.f, 0.f};
    float accm[12] = {0.f};

    #pragma unroll 2
    for (int i = beg; i < end; ++i) {
        const int2 c2 = csr2[i];
        const int e   = c2.x & 0xFFFFF;
        const int src = c2.y;

        const float4 ef = *(const float4*)(edge_feat + (size_t)e * 4);
        const float e0  = ef.x, e1x = ef.y, e1y = ef.z, e1z = ef.w;

        const _Float16* wrow = w16 + (size_t)i * 128 + 4 * j;   // sequential stream
        const half4v w0 = *(const half4v*)(wrow);
        const half4v w1 = *(const half4v*)(wrow + 32);
        const half4v w2 = *(const half4v*)(wrow + 64);
        const half4v w3 = *(const half4v*)(wrow + 96);

        const float* xr = node_feat + (size_t)src * 128;
        const float4 x0v = *(const float4*)(xr + 4 * j);
        const float4 xa  = *(const float4*)(xr + 32 + 12 * j);
        const float4 xb  = *(const float4*)(xr + 36 + 12 * j);
        const float4 xc  = *(const float4*)(xr + 40 + 12 * j);
        const float x0[4]  = {x0v.x, x0v.y, x0v.z, x0v.w};
        const float xx[12] = {xa.x, xa.y, xa.z, xa.w,
                              xb.x, xb.y, xb.z, xb.w,
                              xc.x, xc.y, xc.z, xc.w};
        #pragma unroll
        for (int k = 0; k < 4; ++k) {
            const float x1x = xx[3 * k], x1y = xx[3 * k + 1], x1z = xx[3 * k + 2];
            const float dot = x1x * e1x + x1y * e1y + x1z * e1z;
            acc0[k] += S2 * (float)w0[k] * x0[k] * e0 + S2_3 * (float)w3[k] * dot;
            const float a = S2 * (float)w1[k] * x0[k];
            const float b = S2 * (float)w2[k] * e0;
            accm[3 * k + 0] += a * e1x + b * x1x;
            accm[3 * k + 1] += a * e1y + b * x1y;
            accm[3 * k + 2] += a * e1z + b * x1z;
        }
    }

    // ---- fused self-connection ----
    float s0[4]  = {0.f, 0.f, 0.f, 0.f};
    float s1[12] = {0.f};
    {
        const float* xr = xown + local * 129;
        #pragma unroll 4
        for (int u = 0; u < 32; ++u) {
            const float a0 = xr[u];
            const float ax = xr[32 + 3 * u], ay = xr[33 + 3 * u], az = xr[34 + 3 * u];
            const float* w0r = sw0 + u * 32 + 4 * j;
            const float* w1r = sw1 + u * 32 + 4 * j;
            #pragma unroll
            for (int k = 0; k < 4; ++k) {
                s0[k] += a0 * w0r[k];
                const float wv = w1r[k];
                s1[3 * k + 0] += ax * wv;
                s1[3 * k + 1] += ay * wv;
                s1[3 * k + 2] += az * wv;
            }
        }
    }

    // ---- writeout: out = agg + sc ----
    {
        float* op = out + (size_t)n * 128;
        float4 o0 = {acc0[0] + s0[0] * INV_SQRT_MUL,
                     acc0[1] + s0[1] * INV_SQRT_MUL,
                     acc0[2] + s0[2] * INV_SQRT_MUL,
                     acc0[3] + s0[3] * INV_SQRT_MUL};
        *(float4*)(op + 4 * j) = o0;

        float* mp = op + 32 + 12 * j;
        float4 m0 = {accm[0] + s1[0] * INV_SQRT_MUL,
                     accm[1] + s1[1] * INV_SQRT_MUL,
                     accm[2] + s1[2] * INV_SQRT_MUL,
                     accm[3] + s1[3] * INV_SQRT_MUL};
        float4 m1 = {accm[4] + s1[4] * INV_SQRT_MUL,
                     accm[5] + s1[5] * INV_SQRT_MUL,
                     accm[6] + s1[6] * INV_SQRT_MUL,
                     accm[7] + s1[7] * INV_SQRT_MUL};
        float4 m2 = {accm[8]  + s1[8]  * INV_SQRT_MUL,
                     accm[9]  + s1[9]  * INV_SQRT_MUL,
                     accm[10] + s1[10] * INV_SQRT_MUL,
                     accm[11] + s1[11] * INV_SQRT_MUL};
        *(float4*)(mp)     = m0;
        *(float4*)(mp + 4) = m1;
        *(float4*)(mp + 8) = m2;
    }
}

// ---------------- fused fallback (round-4 gather): used only if ws too small ----------------
__global__ __launch_bounds__(256, 2)
void gather_fused_kernel(const int* __restrict__ ei,
                         const int* __restrict__ row_ptr,
                         const int2* __restrict__ csr2,
                         const float* __restrict__ node_feat,
                         const float* __restrict__ edge_feat,
                         const float* __restrict__ edge_embed,
                         const _Float16* __restrict__ frags,
                         const float* __restrict__ B1,
                         const float* __restrict__ B2,
                         const float* __restrict__ B3,
                         float* __restrict__ out)
{
    __shared__ float    accum[NPB * ACC_STRIDE];
    __shared__ _Float16 H1b[4][16 * H1S];
    __shared__ _Float16 H2b[4][16 * H2S];
    __shared__ float    Wld[4][16 * WSTR];

    const int t  = threadIdx.x;
    const int w  = t >> 6;
    const int l  = t & 63;
    const int lg = l >> 4;
    const int lr = l & 15;

    const half8* f8 = (const half8*)frags;
    half8 w1f[4], w2f[2][2], w3f[8];
    #pragma unroll
    for (int i = 0; i < 4; ++i) w1f[i] = f8[i * 64 + l];
    #pragma unroll
    for (int kc = 0; kc < 2; ++kc)
        #pragma unroll
        for (int i = 0; i < 2; ++i) w2f[kc][i] = f8[256 + kc * 128 + i * 64 + l];
    #pragma unroll
    for (int i = 0; i < 8; ++i) w3f[i] = f8[512 + i * 64 + l];

    float b1r[4], b2r[2], b3r[8];
    #pragma unroll
    for (int i = 0; i < 4; ++i) b1r[i] = B1[i * 16 + lr];
    #pragma unroll
    for (int i = 0; i < 2; ++i) b2r[i] = B2[i * 16 + lr];
    #pragma unroll
    for (int i = 0; i < 8; ++i) b3r[i] = B3[i * 16 + lr];

    for (int i = t; i < NPB * ACC_STRIDE; i += 256) accum[i] = 0.0f;
    __syncthreads();

    const int node_base = blockIdx.x * NPB;
    const int nb_end    = (node_base + NPB < N_NODES) ? node_base + NPB : N_NODES;
    const int start     = row_ptr[node_base];
    const int end       = row_ptr[nb_end];
    const int cnt       = end - start;

    const floatx4 zero = {0.f, 0.f, 0.f, 0.f};
    _Float16* h1p = H1b[w];
    _Float16* h2p = H2b[w];
    float*    wp  = Wld[w];

    for (int tile = w; tile * 16 < cnt; tile += 4) {
        const int tb = start + tile * 16;
        const int iM  = tb + lr;
        const int iiM = (iM < end) ? iM : end - 1;
        const int eM  = csr2[iiM].x & 0xFFFFF;

        const int  q    = l & 3;
        const int  edg  = l >> 2;
        const int  iX   = tb + edg;
        const bool vX   = iX < end;
        const int  iiX  = vX ? iX : end - 1;
        const int2 enX  = csr2[iiX];
        const int  eX   = enX.x & 0xFFFFF;
        const int  locX = (enX.x >> 20) & (NPB - 1);
        const int  srcX = enX.y;

        float4 efX = {0.f, 0.f, 0.f, 0.f};
        if (vX) efX = *(const float4*)(edge_feat + (size_t)eX * 4);

        const float* xr = node_feat + (size_t)srcX * 128;
        float4 x0h[2], x1h[2][3];
        #pragma unroll
        for (int h = 0; h < 2; ++h) {
            x0h[h] = *(const float4*)(xr + h * 16 + q * 4);
            const float* xb = xr + 32 + 48 * h + 12 * q;
            x1h[h][0] = *(const float4*)(xb);
            x1h[h][1] = *(const float4*)(xb + 4);
            x1h[h][2] = *(const float4*)(xb + 8);
        }

        const float* ep = edge_embed + (size_t)eM * 32 + lg * 8;
        const float4 ea = *(const float4*)ep;
        const float4 eb = *(const float4*)(ep + 4);
        half8 a1;
        a1[0] = (_Float16)ea.x; a1[1] = (_Float16)ea.y;
        a1[2] = (_Float16)ea.z; a1[3] = (_Float16)ea.w;
        a1[4] = (_Float16)eb.x; a1[5] = (_Float16)eb.y;
        a1[6] = (_Float16)eb.z; a1[7] = (_Float16)eb.w;

        #pragma unroll
        for (int tt = 0; tt < 4; ++tt) {
            floatx4 c = __builtin_amdgcn_mfma_f32_16x16x32_f16(a1, w1f[tt], zero, 0, 0, 0);
            #pragma unroll
            for (int r = 0; r < 4; ++r) {
                const float v = silu_f(c[r] + b1r[tt]);
                h1p[(lg * 4 + r) * H1S + tt * 16 + lr] = (_Float16)v;
            }
        }
        const half8 a2_0 = *(const half8*)&h1p[lr * H1S +      lg * 8];
        const half8 a2_1 = *(const half8*)&h1p[lr * H1S + 32 + lg * 8];

        #pragma unroll
        for (int tt = 0; tt < 2; ++tt) {
            floatx4 c = __builtin_amdgcn_mfma_f32_16x16x32_f16(a2_0, w2f[0][tt], zero, 0, 0, 0);
            c = __builtin_amdgcn_mfma_f32_16x16x32_f16(a2_1, w2f[1][tt], c, 0, 0, 0);
            #pragma unroll
            for (int r = 0; r < 4; ++r) {
                const float v = silu_f(c[r] + b2r[tt]);
                h2p[(lg * 4 + r) * H2S + tt * 16 + lr] = (_Float16)v;
            }
        }
        const half8 a3 = *(const half8*)&h2p[lr * H2S + lg * 8];

        float* arow = accum + locX * ACC_STRIDE;
        #pragma unroll
        for (int h = 0; h < 2; ++h) {
            #pragma unroll
            for (int ttt = 0; ttt < 4; ++ttt) {
                const int tt = ttt * 2 + h;
                floatx4 c = __builtin_amdgcn_mfma_f32_16x16x32_f16(a3, w3f[tt], zero, 0, 0, 0);
                #pragma unroll
                for (int r = 0; r < 4; ++r)
                    wp[(lg * 4 + r) * WSTR + ttt * 16 + lr] = c[r] + b3r[tt];
            }

            const float4 w0v = *(const float4*)&wp[edg * WSTR +      q * 4];
            const float4 w1v = *(const float4*)&wp[edg * WSTR + 16 + q * 4];
            const float4 w2v = *(const float4*)&wp[edg * WSTR + 32 + q * 4];
            const float4 w3v = *(const float4*)&wp[edg * WSTR + 48 + q * 4];
            const float wa0[4] = {w0v.x, w0v.y, w0v.z, w0v.w};
            const float wa1[4] = {w1v.x, w1v.y, w1v.z, w1v.w};
            const float wa2[4] = {w2v.x, w2v.y, w2v.z, w2v.w};
            const float wa3[4] = {w3v.x, w3v.y, w3v.z, w3v.w};

            const float e0  = efX.x, e1x = efX.y, e1y = efX.z, e1z = efX.w;
            const float x0a[4] = {x0h[h].x, x0h[h].y, x0h[h].z, x0h[h].w};
            const float xx[12] = {x1h[h][0].x, x1h[h][0].y, x1h[h][0].z, x1h[h][0].w,
                                  x1h[h][1].x, x1h[h][1].y, x1h[h][1].z, x1h[h][1].w,
                                  x1h[h][2].x, x1h[h][2].y, x1h[h][2].z, x1h[h][2].w};
            #pragma unroll
            for (int k = 0; k < 4; ++k) {
                const int u = h * 16 + q * 4 + k;
                const float x1x = xx[3 * k], x1y = xx[3 * k + 1], x1z = xx[3 * k + 2];
                const float dot = x1x * e1x + x1y * e1y + x1z * e1z;
                const float o0  = S2 * wa0[k] * x0a[k] * e0 + S2_3 * wa3[k] * dot;
                const float a   = S2 * wa1[k] * x0a[k];
                const float b   = S2 * wa2[k] * e0;
                atomicAdd(arow + u,              o0);
                atomicAdd(arow + 32 + 3 * u + 0, a * e1x + b * x1x);
                atomicAdd(arow + 32 + 3 * u + 1, a * e1y + b * x1y);
                atomicAdd(arow + 32 + 3 * u + 2, a * e1z + b * x1z);
            }
        }
    }
    __syncthreads();

    for (int i = t; i < NPB * 32; i += 256) {
        const int local = i >> 5;
        const int f4    = i & 31;
        const int n     = node_base + local;
        if (n < N_NODES) {
            float* op = out + (size_t)n * 128 + f4 * 4;
            float4 o = *(float4*)op;
            const float* ar = accum + local * ACC_STRIDE + f4 * 4;
            o.x += ar[0]; o.y += ar[1]; o.z += ar[2]; o.w += ar[3];
            *(float4*)op = o;
        }
    }
}

extern "C" void kernel_launch(void* const* d_in, const int* in_sizes, int n_in,
                              void* d_out, int out_size, void* d_ws, size_t ws_size,
                              hipStream_t stream)
{
    const int*   ei         = (const int*)  d_in[0];
    const float* node_feat  = (const float*)d_in[1];
    const float* edge_feat  = (const float*)d_in[2];
    const float* edge_embed = (const float*)d_in[3];
    const float* fc_w1      = (const float*)d_in[4];
    const float* fc_b1      = (const float*)d_in[5];
    const float* fc_w2      = (const float*)d_in[6];
    const float* fc_b2      = (const float*)d_in[7];
    const float* fc_w3      = (const float*)d_in[8];
    const float* fc_b3      = (const float*)d_in[9];
    const float* sc_w0      = (const float*)d_in[10];
    const float* sc_w1      = (const float*)d_in[11];
    float* out = (float*)d_out;

    // workspace (int offsets): counts | row_ptr | cursor | bsum | boff | csr2 | frags | w16
    int*  ws      = (int*)d_ws;
    int*  counts  = ws;                                       // N_NODES
    int*  row_ptr = ws + 51200;                               // N_NODES+1
    int*  cursor  = ws + 102400;                              // N_NODES
    int*  bsum    = ws + 153600;                              // NB_SCAN
    int*  boff    = ws + 153856;                              // NB_SCAN
    int2* csr2    = (int2*)(ws + 154112);                     // byte 616448, 6.4 MB
    _Float16* frags = (_Float16*)((char*)d_ws + 7016448);     // 16 KB
    _Float16* w16   = (_Float16*)((char*)d_ws + 7032832);     // 204.8 MB
    const bool big_ws = (ws_size >= 7032832ULL + 204800000ULL);

    hipMemsetAsync(counts, 0, N_NODES * sizeof(int), stream);

    hist_kernel     <<<(N_EDGES / 4 + 255) / 256, 256, 0, stream>>>(ei, counts);
    bsum_kernel     <<<NB_SCAN, 256, 0, stream>>>(counts, cursor, bsum);
    scan_sums_kernel<<<2, 256, 0, stream>>>(bsum, boff, row_ptr,
                                            fc_w1, fc_w2, fc_w3, frags);
    apply_kernel    <<<NB_SCAN, 256, 0, stream>>>(boff, cursor, row_ptr);
    scatter_kernel  <<<N_EDGES / 256, 256, 0, stream>>>(ei, cursor, csr2);

    if (big_ws) {
        mlp_kernel<<<3125, 256, 0, stream>>>(csr2, edge_embed, frags, fc_b1, fc_b2, fc_b3, w16);
        gather2_kernel<<<N_NODES / NPB2, 128, 0, stream>>>(csr2, row_ptr,
                                                           node_feat, edge_feat, w16,
                                                           sc_w0, sc_w1, out);
    } else {
        sc_kernel<<<N_NODES / 8, 256, 0, stream>>>(node_feat, sc_w0, sc_w1, out);
        gather_fused_kernel<<<(N_NODES + NPB - 1) / NPB, 256, 0, stream>>>(
            ei, row_ptr, csr2, node_feat, edge_feat, edge_embed,
            frags, fc_b1, fc_b2, fc_b3, out);
    }
}